// Round 6
// baseline (467.727 us; speedup 1.0000x reference)
//
#include <hip/hip_runtime.h>
#include <hip/hip_bf16.h>
#include <math.h>

#define D_ 256
#define B_ 65536
#define C_ 1000

typedef _Float16 f16x8 __attribute__((ext_vector_type(8)));
typedef _Float16 f16x4 __attribute__((ext_vector_type(4)));
typedef float f32x4 __attribute__((ext_vector_type(4)));

// ---------------- kernel 0: transpose bc (256x256 f32) + zero loss acc ----------------
__global__ void transpose_kernel(const float* __restrict__ in, float* __restrict__ out,
                                 double* __restrict__ acc) {
  __shared__ float t[32][33];
  if (blockIdx.x == 0 && threadIdx.x == 0) *acc = 0.0;
  const int bx = blockIdx.x & 7, by = blockIdx.x >> 3;
  const int lx = threadIdx.x & 31, ly = threadIdx.x >> 5;  // 32 x 8
#pragma unroll
  for (int s = 0; s < 4; ++s) {
    int r = by * 32 + ly + s * 8;
    t[ly + s * 8][lx] = in[r * 256 + bx * 32 + lx];
  }
  __syncthreads();
#pragma unroll
  for (int s = 0; s < 4; ++s) {
    int r = bx * 32 + ly + s * 8;
    out[r * 256 + by * 32 + lx] = t[lx][ly + s * 8];
  }
}

// ---------------- kernel 1: cov = bc @ bc^T in fp64 (coalesced via bcT) ----------------
__global__ void cov_kernel(const float* __restrict__ bc, const float* __restrict__ bcT,
                           double* __restrict__ C64) {
  const int i = blockIdx.x, j = threadIdx.x;
  __shared__ float ri[D_];
  ri[j] = bc[i * D_ + j];
  __syncthreads();
  double s = 0.0;
#pragma unroll 8
  for (int k = 0; k < D_; ++k) s += (double)ri[k] * (double)bcT[k * D_ + j];
  C64[i * D_ + j] = s;
}

// ---------------- kernel 2a: factor panel p (64 cols), rows in registers ----------------
__global__ __launch_bounds__(256, 1) void chol_panel(double* __restrict__ A, int p) {
  const int j0 = p * 64;
  const int r = threadIdx.x;
  __shared__ double rowv[64];
  __shared__ double dinv;
  double pr[64];
  const bool act = (r >= j0);
  if (act) {
#pragma unroll
    for (int k = 0; k < 64; ++k) pr[k] = A[(size_t)r * D_ + j0 + k];
  }
#pragma unroll
  for (int j = 0; j < 64; ++j) {
    const int col = j0 + j;
    if (r == col) { double d = sqrt(pr[j]); pr[j] = d; dinv = 1.0 / d; }
    __syncthreads();
    if (r > col) {
      double lr = pr[j] * dinv;
      pr[j] = lr;
      if (r < j0 + 64) rowv[r - j0] = lr;
    }
    __syncthreads();
    if (r > col) {
      const double lr = pr[j];
#pragma unroll
      for (int k = j + 1; k < 64; ++k) pr[k] -= lr * rowv[k];
    }
  }
  if (act) {
    const int kmax = (r - j0 < 63) ? (r - j0) : 63;
#pragma unroll
    for (int k = 0; k < 64; ++k)
      if (k <= kmax) A[(size_t)r * D_ + j0 + k] = pr[k];
  }
}

// ---------------- kernel 2b: trailing update for panel p, one block per 64x64 tile ----
__global__ __launch_bounds__(256) void chol_trail(double* __restrict__ A, int p) {
  const int j0 = p * 64;
  const int t0 = j0 + 64;
  int b = blockIdx.x, I = 0;
  while (b >= I + 1) { b -= I + 1; ++I; }   // lower tile pair (I,J), J<=I
  const int J = b;
  const int r0 = t0 + I * 64, c0 = t0 + J * 64;
  __shared__ double LR[64][67];
  __shared__ double LC[64][67];
  const int tid = threadIdx.x;
  for (int e = tid; e < 64 * 64; e += 256) {
    int rr = e >> 6, cc = e & 63;
    LR[rr][cc] = A[(size_t)(r0 + rr) * D_ + j0 + cc];
    LC[rr][cc] = A[(size_t)(c0 + rr) * D_ + j0 + cc];
  }
  __syncthreads();
  const int tx = tid & 15, ty = tid >> 4;
  double acc[4][4];
#pragma unroll
  for (int i = 0; i < 4; ++i)
#pragma unroll
    for (int j = 0; j < 4; ++j) acc[i][j] = 0.0;
#pragma unroll 4
  for (int k = 0; k < 64; ++k) {
    double a_[4], b_[4];
#pragma unroll
    for (int i = 0; i < 4; ++i) a_[i] = LR[ty + 16 * i][k];
#pragma unroll
    for (int j = 0; j < 4; ++j) b_[j] = LC[tx + 16 * j][k];
#pragma unroll
    for (int i = 0; i < 4; ++i)
#pragma unroll
      for (int j = 0; j < 4; ++j) acc[i][j] += a_[i] * b_[j];
  }
#pragma unroll
  for (int i = 0; i < 4; ++i) {
    const int grow = r0 + ty + 16 * i;
#pragma unroll
    for (int j = 0; j < 4; ++j) {
      const int gcol = c0 + tx + 16 * j;
      A[(size_t)grow * D_ + gcol] -= acc[i][j];
    }
  }
}

// ---------------- kernel 3: W = L^-1 column c + direct f16 emit (convert folded in) ---
__global__ __launch_bounds__(256) void inv_kernel(const double* __restrict__ L,
                                                  _Float16* __restrict__ Wb,
                                                  _Float16* __restrict__ WbT) {
  const int c = blockIdx.x;
  const int tid = threadIdx.x;
  __shared__ double w[D_];
  __shared__ double rdi[D_];
  __shared__ double rhs[32];
  __shared__ double Ldd[32][33];
  w[tid] = 0.0;
  rdi[tid] = 1.0 / L[(size_t)tid * D_ + tid];
  __syncthreads();
  const int q0 = c >> 5;
  for (int q = q0; q < 8; ++q) {
    const int i0 = q * 32;
    const int ii = tid >> 3, s = tid & 7;
    const int i = i0 + ii;
    double part = 0.0;
    for (int k = c + s; k < i0; k += 8) part += L[(size_t)i * D_ + k] * w[k];
    part += __shfl_xor(part, 1, 64);
    part += __shfl_xor(part, 2, 64);
    part += __shfl_xor(part, 4, 64);
    if (s == 0) rhs[ii] = ((i == c) ? 1.0 : 0.0) - part;
    for (int e = tid; e < 32 * 32; e += 256) {
      int rr = e >> 5, cc = e & 31;
      Ldd[rr][cc] = L[(size_t)(i0 + rr) * D_ + i0 + cc];
    }
    __syncthreads();
    if (tid < 32) {
      double x = rhs[tid];
      double v = 0.0;
      for (int j = 0; j < 32; ++j) {
        double xj = __shfl(x, j, 64);
        double wj = xj * rdi[i0 + j];
        if (tid == j) v = wj;
        if (tid > j) x -= Ldd[tid][j] * wj;
      }
      w[i0 + tid] = v;
    }
    __syncthreads();
  }
  _Float16 h = (_Float16)(float)w[tid];
  WbT[(size_t)c * D_ + tid] = h;   // WbT[k=c][i=tid], coalesced
  Wb[(size_t)tid * D_ + c] = h;    // Wb[i=tid][k=c]
}

// ---------------- kernel 5: signatures, normalized, packed MFMA-fragment layout -------
// sHatP element layout: block (g,ks) of 512 elems at ((g*8+ks)*512); within it,
// chunk l (l=0..63) = 8 elems: col = g*16 + (l&15), k = ks*32 + (l>>4)*8 .. +7.
__global__ void sig_kernel(const float* __restrict__ S, const _Float16* __restrict__ WbT,
                           _Float16* __restrict__ sHatP) {
  int c = blockIdx.x, i = threadIdx.x;
  const int g = c >> 4, lr = c & 15;
  const int ks = i >> 5, lq = (i >> 3) & 3, jj = i & 7;
  const size_t off = (size_t)(g * 8 + ks) * 512 + (size_t)(lq * 16 + lr) * 8 + jj;
  if (c >= C_) { sHatP[off] = (_Float16)0.0f; return; }  // pad classes exactly 0
  __shared__ float srow[D_];
  __shared__ float wred[4];
  srow[i] = S[c * D_ + i];
  __syncthreads();
  float t = 0.f;
  for (int k = 0; k < D_; ++k) t += (float)WbT[k * D_ + i] * srow[k];
  float ss = t * t;
#pragma unroll
  for (int d = 1; d < 64; d <<= 1) ss += __shfl_xor(ss, d, 64);
  if ((i & 63) == 0) wred[i >> 6] = ss;
  __syncthreads();
  float tot = wred[0] + wred[1] + wred[2] + wred[3];
  float rn = 1.0f / fmaxf(sqrtf(tot), 1e-12f);
  sHatP[off] = (_Float16)(t * rn);
}

// ---------------- kernel 6: xHat_un = (X - m) @ W^T (MFMA), rnX per row ----------------
__global__ __launch_bounds__(256) void xform_kernel(const float* __restrict__ X,
                                                    const float* __restrict__ means,
                                                    const _Float16* __restrict__ Wb,
                                                    _Float16* __restrict__ xHat,
                                                    float* __restrict__ rnX) {
  __shared__ __align__(16) _Float16 As[64 * D_];   // 32 KB, swizzled
  __shared__ __align__(16) _Float16 Bs[128 * D_];  // 64 KB, swizzled
  __shared__ float msh[D_];
  const int tid = threadIdx.x;
  const int rowbase = blockIdx.x * 64;
  msh[tid] = means[tid];
  __syncthreads();
  for (int s = 0; s < 16; ++s) {
    int c = s * 256 + tid;
    int r = c >> 6, q = c & 63;
    const float4 xv = *(const float4*)(X + (size_t)(rowbase + r) * D_ + q * 4);
    f16x4 hv;
    hv[0] = (_Float16)(xv.x - msh[q * 4 + 0]);
    hv[1] = (_Float16)(xv.y - msh[q * 4 + 1]);
    hv[2] = (_Float16)(xv.z - msh[q * 4 + 2]);
    hv[3] = (_Float16)(xv.w - msh[q * 4 + 3]);
    int byte = (q * 8) ^ ((r & 7) << 4);
    *(f16x4*)((char*)(As + r * D_) + byte) = hv;
  }
  const int w = tid >> 6, l = tid & 63, lr = l & 15, lq = l >> 4;
  float ss[4] = {0.f, 0.f, 0.f, 0.f};
  for (int ch = 0; ch < 2; ++ch) {
    __syncthreads();
    for (int s = 0; s < 16; ++s) {
      int c = s * 256 + tid;
      int r = c >> 5, q = c & 31;
      uint4 v = *(const uint4*)(Wb + (size_t)(ch * 128 + r) * D_ + q * 8);
      int byte = (q * 16) ^ ((r & 7) << 4);
      *(uint4*)((char*)(Bs + r * D_) + byte) = v;
    }
    __syncthreads();
    f32x4 acc[8];
#pragma unroll
    for (int t = 0; t < 8; ++t) acc[t] = (f32x4){0.f, 0.f, 0.f, 0.f};
#pragma unroll
    for (int ks = 0; ks < 8; ++ks) {
      int arow = w * 16 + lr;
      int abyte = (ks * 64 + lq * 16) ^ ((arow & 7) << 4);
      f16x8 af = *(const f16x8*)((char*)(As + arow * D_) + abyte);
#pragma unroll
      for (int t = 0; t < 8; ++t) {
        int brow = t * 16 + lr;
        int bbyte = (ks * 64 + lq * 16) ^ ((brow & 7) << 4);
        f16x8 bf = *(const f16x8*)((char*)(Bs + brow * D_) + bbyte);
        acc[t] = __builtin_amdgcn_mfma_f32_16x16x32_f16(af, bf, acc[t], 0, 0, 0);
      }
    }
#pragma unroll
    for (int t = 0; t < 8; ++t) {
      int col = ch * 128 + t * 16 + lr;
#pragma unroll
      for (int j = 0; j < 4; ++j) {
        int row = rowbase + w * 16 + lq * 4 + j;
        float v = acc[t][j];
        ss[j] += v * v;
        xHat[(size_t)row * D_ + col] = (_Float16)v;
      }
    }
  }
#pragma unroll
  for (int d = 1; d < 16; d <<= 1) {
#pragma unroll
    for (int j = 0; j < 4; ++j) ss[j] += __shfl_xor(ss[j], d, 64);
  }
  if (lr == 0) {
#pragma unroll
    for (int j = 0; j < 4; ++j) {
      int row = rowbase + w * 16 + lq * 4 + j;
      rnX[row] = 1.0f / fmaxf(sqrtf(ss[j]), 1e-12f);
    }
  }
}

// ---------------- kernel 8: LDS-free register GEMM, M=32/wave (2 row-tiles) -----------
// Each B fragment (contiguous 1KB wave read from packed L2-resident sHatP) feeds TWO
// MFMAs -> 2x arithmetic intensity per load, half the L2 B-traffic of the M=16 version.
// No barriers in the main loop. Fixed-max logsumexp (cosines <= 1).
__global__ __launch_bounds__(256, 2) void ace_kernel(const _Float16* __restrict__ xHat,
                                                     const _Float16* __restrict__ sHatP,
                                                     const float* __restrict__ rnX,
                                                     const int* __restrict__ labels,
                                                     float* __restrict__ outACE,
                                                     double* __restrict__ acc_loss) {
  __shared__ float part[16];
  const int tid = threadIdx.x;
  const int w = tid >> 6, l = tid & 63, lr = l & 15, lq = l >> 4;
  const int rowbase = blockIdx.x * 128;
  const int wrow = rowbase + w * 32;            // this wave's 32-row strip

  // A fragments for both 16-row tiles (k = ks*32 + lq*8 .. +7)
  f16x8 a0[8], a1[8];
  {
    const _Float16* ap0 = xHat + (size_t)(wrow + lr) * D_ + lq * 8;
    const _Float16* ap1 = xHat + (size_t)(wrow + 16 + lr) * D_ + lq * 8;
#pragma unroll
    for (int ks = 0; ks < 8; ++ks) {
      a0[ks] = *(const f16x8*)(ap0 + ks * 32);
      a1[ks] = *(const f16x8*)(ap1 + ks * 32);
    }
  }

  int lab0[4], lab1[4];
  float rx0[4], rx1[4], ssum0[4], ssum1[4], num0[4], num1[4];
#pragma unroll
  for (int j = 0; j < 4; ++j) {
    int r0 = wrow + lq * 4 + j, r1 = r0 + 16;   // C-layout rows
    lab0[j] = labels[r0]; rx0[j] = rnX[r0]; ssum0[j] = 0.f; num0[j] = 0.f;
    lab1[j] = labels[r1]; rx1[j] = rnX[r1]; ssum1[j] = 0.f; num1[j] = 0.f;
  }

  const _Float16* bl = sHatP + (size_t)l * 8;   // lane's chunk within each 1KB block
  float* const outr0 = outACE + (size_t)(wrow + lq * 4) * C_;
  float* const outr1 = outACE + (size_t)(wrow + 16 + lq * 4) * C_;

  for (int ch = 0; ch < 8; ++ch) {
    f32x4 acc0[8], acc1[8];
#pragma unroll
    for (int t = 0; t < 8; ++t) {
      acc0[t] = (f32x4){0.f, 0.f, 0.f, 0.f};
      acc1[t] = (f32x4){0.f, 0.f, 0.f, 0.f};
    }
#pragma unroll
    for (int ks = 0; ks < 8; ++ks) {
#pragma unroll
      for (int t = 0; t < 8; ++t) {
        f16x8 bf = *(const f16x8*)(bl + (size_t)((ch * 8 + t) * 8 + ks) * 512);
        acc0[t] = __builtin_amdgcn_mfma_f32_16x16x32_f16(a0[ks], bf, acc0[t], 0, 0, 0);
        acc1[t] = __builtin_amdgcn_mfma_f32_16x16x32_f16(a1[ks], bf, acc1[t], 0, 0, 0);
      }
    }
#pragma unroll
    for (int t = 0; t < 8; ++t) {
      const int col = ch * 128 + t * 16 + lr;
      const bool valid = (col < C_);
#pragma unroll
      for (int j = 0; j < 4; ++j) {
        float v0 = acc0[t][j] * rx0[j];
        float v1 = acc1[t][j] * rx1[j];
        if (valid) {
          outr0[(size_t)j * C_ + col] = v0;
          outr1[(size_t)j * C_ + col] = v1;
        }
        ssum0[j] += __expf(v0 - 1.0f);
        ssum1[j] += __expf(v1 - 1.0f);
        num0[j] = (col == lab0[j]) ? v0 : num0[j];
        num1[j] = (col == lab1[j]) ? v1 : num1[j];
      }
    }
  }
#pragma unroll
  for (int d2 = 1; d2 < 16; d2 <<= 1) {
#pragma unroll
    for (int j = 0; j < 4; ++j) {
      ssum0[j] += __shfl_xor(ssum0[j], d2, 64);
      ssum1[j] += __shfl_xor(ssum1[j], d2, 64);
      num0[j]  += __shfl_xor(num0[j], d2, 64);
      num1[j]  += __shfl_xor(num1[j], d2, 64);
    }
  }
  if (lr == 0) {
    const float padcorr = 24.0f * __expf(-1.0f);
    float contrib = 0.f;
#pragma unroll
    for (int j = 0; j < 4; ++j) {
      contrib += num0[j] - (1.0f + __logf(ssum0[j] - padcorr));
      contrib += num1[j] - (1.0f + __logf(ssum1[j] - padcorr));
    }
    part[w * 4 + lq] = contrib;
  }
  __syncthreads();
  if (tid == 0) {
    float s = 0.f;
#pragma unroll
    for (int p2 = 0; p2 < 16; ++p2) s += part[p2];
    atomicAdd(acc_loss, (double)s);
  }
}

// ---------------- kernel 9: finalize loss ----------------
__global__ void fin_kernel(const double* a, float* out) {
  out[0] = (float)(-(*a) / (double)B_);
}

extern "C" void kernel_launch(void* const* d_in, const int* in_sizes, int n_in,
                              void* d_out, int out_size, void* d_ws, size_t ws_size,
                              hipStream_t stream) {
  const float* X      = (const float*)d_in[0];
  const int*   labels = (const int*)d_in[1];
  const float* S      = (const float*)d_in[2];
  const float* means  = (const float*)d_in[3];
  const float* bc     = (const float*)d_in[4];
  float* out = (float*)d_out;

  char* w = (char*)d_ws;
  double*    acc   = (double*)(w + 0);
  double*    C64   = (double*)(w + 256);          // 512 KB
  _Float16*  Wb    = (_Float16*)(w + 524544);     // 128 KB
  _Float16*  WbT   = (_Float16*)(w + 655616);     // 128 KB
  _Float16*  sHatP = (_Float16*)(w + 786688);     // 512 KB packed (1024 classes)
  float*     rnX   = (float*)(w + 1310976);       // 256 KB
  _Float16*  xHat  = (_Float16*)(w + 1573120);    // 32 MB
  float*     bcT   = (float*)(w + 1573120);       // aliases xHat (used before xform)

  transpose_kernel<<<64, 256, 0, stream>>>(bc, bcT, acc);
  cov_kernel<<<256, 256, 0, stream>>>(bc, bcT, C64);
  for (int p = 0; p < 4; ++p) {
    chol_panel<<<1, 256, 0, stream>>>(C64, p);
    int nt = 3 - p;
    if (nt > 0) chol_trail<<<nt * (nt + 1) / 2, 256, 0, stream>>>(C64, p);
  }
  inv_kernel<<<256, 256, 0, stream>>>(C64, Wb, WbT);
  sig_kernel<<<1024, 256, 0, stream>>>(S, WbT, sHatP);
  xform_kernel<<<1024, 256, 0, stream>>>(X, means, Wb, xHat, rnX);
  ace_kernel<<<512, 256, 0, stream>>>(xHat, sHatP, rnX, labels, out + 1, acc);
  fin_kernel<<<1, 1, 0, stream>>>(acc, out);
}

// Round 7
// 388.319 us; speedup vs baseline: 1.2045x; 1.2045x over previous
//
#include <hip/hip_runtime.h>
#include <hip/hip_bf16.h>
#include <math.h>

#define D_ 256
#define B_ 65536
#define C_ 1000

typedef _Float16 f16x8 __attribute__((ext_vector_type(8)));
typedef _Float16 f16x4 __attribute__((ext_vector_type(4)));
typedef float f32x4 __attribute__((ext_vector_type(4)));

// ---------------- kernel 0: transpose bc (256x256 f32) + zero loss acc ----------------
__global__ void transpose_kernel(const float* __restrict__ in, float* __restrict__ out,
                                 double* __restrict__ acc) {
  __shared__ float t[32][33];
  if (blockIdx.x == 0 && threadIdx.x == 0) *acc = 0.0;
  const int bx = blockIdx.x & 7, by = blockIdx.x >> 3;
  const int lx = threadIdx.x & 31, ly = threadIdx.x >> 5;  // 32 x 8
#pragma unroll
  for (int s = 0; s < 4; ++s) {
    int r = by * 32 + ly + s * 8;
    t[ly + s * 8][lx] = in[r * 256 + bx * 32 + lx];
  }
  __syncthreads();
#pragma unroll
  for (int s = 0; s < 4; ++s) {
    int r = bx * 32 + ly + s * 8;
    out[r * 256 + by * 32 + lx] = t[lx][ly + s * 8];
  }
}

// ---------------- kernel 1: cov = bc @ bc^T in fp64 (coalesced via bcT) ----------------
__global__ void cov_kernel(const float* __restrict__ bc, const float* __restrict__ bcT,
                           double* __restrict__ C64) {
  const int i = blockIdx.x, j = threadIdx.x;
  __shared__ float ri[D_];
  ri[j] = bc[i * D_ + j];
  __syncthreads();
  double s = 0.0;
#pragma unroll 8
  for (int k = 0; k < D_; ++k) s += (double)ri[k] * (double)bcT[k * D_ + j];
  C64[i * D_ + j] = s;
}

// ---------------- kernel 2a: factor panel p (64 cols), rows in registers ----------------
__global__ __launch_bounds__(256, 1) void chol_panel(double* __restrict__ A, int p) {
  const int j0 = p * 64;
  const int r = threadIdx.x;
  __shared__ double rowv[64];
  __shared__ double dinv;
  double pr[64];
  const bool act = (r >= j0);
  if (act) {
#pragma unroll
    for (int k = 0; k < 64; ++k) pr[k] = A[(size_t)r * D_ + j0 + k];
  }
#pragma unroll
  for (int j = 0; j < 64; ++j) {
    const int col = j0 + j;
    if (r == col) { double d = sqrt(pr[j]); pr[j] = d; dinv = 1.0 / d; }
    __syncthreads();
    if (r > col) {
      double lr = pr[j] * dinv;
      pr[j] = lr;
      if (r < j0 + 64) rowv[r - j0] = lr;
    }
    __syncthreads();
    if (r > col) {
      const double lr = pr[j];
#pragma unroll
      for (int k = j + 1; k < 64; ++k) pr[k] -= lr * rowv[k];
    }
  }
  if (act) {
    const int kmax = (r - j0 < 63) ? (r - j0) : 63;
#pragma unroll
    for (int k = 0; k < 64; ++k)
      if (k <= kmax) A[(size_t)r * D_ + j0 + k] = pr[k];
  }
}

// ---------------- kernel 2b: trailing update for panel p, one block per 64x64 tile ----
__global__ __launch_bounds__(256) void chol_trail(double* __restrict__ A, int p) {
  const int j0 = p * 64;
  const int t0 = j0 + 64;
  int b = blockIdx.x, I = 0;
  while (b >= I + 1) { b -= I + 1; ++I; }   // lower tile pair (I,J), J<=I
  const int J = b;
  const int r0 = t0 + I * 64, c0 = t0 + J * 64;
  __shared__ double LR[64][67];
  __shared__ double LC[64][67];
  const int tid = threadIdx.x;
  for (int e = tid; e < 64 * 64; e += 256) {
    int rr = e >> 6, cc = e & 63;
    LR[rr][cc] = A[(size_t)(r0 + rr) * D_ + j0 + cc];
    LC[rr][cc] = A[(size_t)(c0 + rr) * D_ + j0 + cc];
  }
  __syncthreads();
  const int tx = tid & 15, ty = tid >> 4;
  double acc[4][4];
#pragma unroll
  for (int i = 0; i < 4; ++i)
#pragma unroll
    for (int j = 0; j < 4; ++j) acc[i][j] = 0.0;
#pragma unroll 4
  for (int k = 0; k < 64; ++k) {
    double a_[4], b_[4];
#pragma unroll
    for (int i = 0; i < 4; ++i) a_[i] = LR[ty + 16 * i][k];
#pragma unroll
    for (int j = 0; j < 4; ++j) b_[j] = LC[tx + 16 * j][k];
#pragma unroll
    for (int i = 0; i < 4; ++i)
#pragma unroll
      for (int j = 0; j < 4; ++j) acc[i][j] += a_[i] * b_[j];
  }
#pragma unroll
  for (int i = 0; i < 4; ++i) {
    const int grow = r0 + ty + 16 * i;
#pragma unroll
    for (int j = 0; j < 4; ++j) {
      const int gcol = c0 + tx + 16 * j;
      A[(size_t)grow * D_ + gcol] -= acc[i][j];
    }
  }
}

// ---------------- kernel 3: W = L^-1 column c + direct f16 emit (convert folded in) ---
__global__ __launch_bounds__(256) void inv_kernel(const double* __restrict__ L,
                                                  _Float16* __restrict__ Wb,
                                                  _Float16* __restrict__ WbT) {
  const int c = blockIdx.x;
  const int tid = threadIdx.x;
  __shared__ double w[D_];
  __shared__ double rdi[D_];
  __shared__ double rhs[32];
  __shared__ double Ldd[32][33];
  w[tid] = 0.0;
  rdi[tid] = 1.0 / L[(size_t)tid * D_ + tid];
  __syncthreads();
  const int q0 = c >> 5;
  for (int q = q0; q < 8; ++q) {
    const int i0 = q * 32;
    const int ii = tid >> 3, s = tid & 7;
    const int i = i0 + ii;
    double part = 0.0;
    for (int k = c + s; k < i0; k += 8) part += L[(size_t)i * D_ + k] * w[k];
    part += __shfl_xor(part, 1, 64);
    part += __shfl_xor(part, 2, 64);
    part += __shfl_xor(part, 4, 64);
    if (s == 0) rhs[ii] = ((i == c) ? 1.0 : 0.0) - part;
    for (int e = tid; e < 32 * 32; e += 256) {
      int rr = e >> 5, cc = e & 31;
      Ldd[rr][cc] = L[(size_t)(i0 + rr) * D_ + i0 + cc];
    }
    __syncthreads();
    if (tid < 32) {
      double x = rhs[tid];
      double v = 0.0;
      for (int j = 0; j < 32; ++j) {
        double xj = __shfl(x, j, 64);
        double wj = xj * rdi[i0 + j];
        if (tid == j) v = wj;
        if (tid > j) x -= Ldd[tid][j] * wj;
      }
      w[i0 + tid] = v;
    }
    __syncthreads();
  }
  _Float16 h = (_Float16)(float)w[tid];
  WbT[(size_t)c * D_ + tid] = h;   // WbT[k=c][i=tid], coalesced
  Wb[(size_t)tid * D_ + c] = h;    // Wb[i=tid][k=c]
}

// ---------------- kernel 5: signatures, normalized, packed MFMA-fragment layout -------
// sHatP element layout: block (g,ks) of 512 elems at ((g*8+ks)*512); within it,
// chunk l (l=0..63) = 8 elems: col = g*16 + (l&15), k = ks*32 + (l>>4)*8 .. +7.
__global__ void sig_kernel(const float* __restrict__ S, const _Float16* __restrict__ WbT,
                           _Float16* __restrict__ sHatP) {
  int c = blockIdx.x, i = threadIdx.x;
  const int g = c >> 4, lr = c & 15;
  const int ks = i >> 5, lq = (i >> 3) & 3, jj = i & 7;
  const size_t off = (size_t)(g * 8 + ks) * 512 + (size_t)(lq * 16 + lr) * 8 + jj;
  if (c >= C_) { sHatP[off] = (_Float16)0.0f; return; }  // pad classes exactly 0
  __shared__ float srow[D_];
  __shared__ float wred[4];
  srow[i] = S[c * D_ + i];
  __syncthreads();
  float t = 0.f;
  for (int k = 0; k < D_; ++k) t += (float)WbT[k * D_ + i] * srow[k];
  float ss = t * t;
#pragma unroll
  for (int d = 1; d < 64; d <<= 1) ss += __shfl_xor(ss, d, 64);
  if ((i & 63) == 0) wred[i >> 6] = ss;
  __syncthreads();
  float tot = wred[0] + wred[1] + wred[2] + wred[3];
  float rn = 1.0f / fmaxf(sqrtf(tot), 1e-12f);
  sHatP[off] = (_Float16)(t * rn);
}

// ---------------- kernel 6: xHat_un = (X - m) @ W^T (MFMA), rnX per row ----------------
__global__ __launch_bounds__(256) void xform_kernel(const float* __restrict__ X,
                                                    const float* __restrict__ means,
                                                    const _Float16* __restrict__ Wb,
                                                    _Float16* __restrict__ xHat,
                                                    float* __restrict__ rnX) {
  __shared__ __align__(16) _Float16 As[64 * D_];   // 32 KB, swizzled
  __shared__ __align__(16) _Float16 Bs[128 * D_];  // 64 KB, swizzled
  __shared__ float msh[D_];
  const int tid = threadIdx.x;
  const int rowbase = blockIdx.x * 64;
  msh[tid] = means[tid];
  __syncthreads();
  for (int s = 0; s < 16; ++s) {
    int c = s * 256 + tid;
    int r = c >> 6, q = c & 63;
    const float4 xv = *(const float4*)(X + (size_t)(rowbase + r) * D_ + q * 4);
    f16x4 hv;
    hv[0] = (_Float16)(xv.x - msh[q * 4 + 0]);
    hv[1] = (_Float16)(xv.y - msh[q * 4 + 1]);
    hv[2] = (_Float16)(xv.z - msh[q * 4 + 2]);
    hv[3] = (_Float16)(xv.w - msh[q * 4 + 3]);
    int byte = (q * 8) ^ ((r & 7) << 4);
    *(f16x4*)((char*)(As + r * D_) + byte) = hv;
  }
  const int w = tid >> 6, l = tid & 63, lr = l & 15, lq = l >> 4;
  float ss[4] = {0.f, 0.f, 0.f, 0.f};
  for (int ch = 0; ch < 2; ++ch) {
    __syncthreads();
    for (int s = 0; s < 16; ++s) {
      int c = s * 256 + tid;
      int r = c >> 5, q = c & 31;
      uint4 v = *(const uint4*)(Wb + (size_t)(ch * 128 + r) * D_ + q * 8);
      int byte = (q * 16) ^ ((r & 7) << 4);
      *(uint4*)((char*)(Bs + r * D_) + byte) = v;
    }
    __syncthreads();
    f32x4 acc[8];
#pragma unroll
    for (int t = 0; t < 8; ++t) acc[t] = (f32x4){0.f, 0.f, 0.f, 0.f};
#pragma unroll
    for (int ks = 0; ks < 8; ++ks) {
      int arow = w * 16 + lr;
      int abyte = (ks * 64 + lq * 16) ^ ((arow & 7) << 4);
      f16x8 af = *(const f16x8*)((char*)(As + arow * D_) + abyte);
#pragma unroll
      for (int t = 0; t < 8; ++t) {
        int brow = t * 16 + lr;
        int bbyte = (ks * 64 + lq * 16) ^ ((brow & 7) << 4);
        f16x8 bf = *(const f16x8*)((char*)(Bs + brow * D_) + bbyte);
        acc[t] = __builtin_amdgcn_mfma_f32_16x16x32_f16(af, bf, acc[t], 0, 0, 0);
      }
    }
#pragma unroll
    for (int t = 0; t < 8; ++t) {
      int col = ch * 128 + t * 16 + lr;
#pragma unroll
      for (int j = 0; j < 4; ++j) {
        int row = rowbase + w * 16 + lq * 4 + j;
        float v = acc[t][j];
        ss[j] += v * v;
        xHat[(size_t)row * D_ + col] = (_Float16)v;
      }
    }
  }
#pragma unroll
  for (int d = 1; d < 16; d <<= 1) {
#pragma unroll
    for (int j = 0; j < 4; ++j) ss[j] += __shfl_xor(ss[j], d, 64);
  }
  if (lr == 0) {
#pragma unroll
    for (int j = 0; j < 4; ++j) {
      int row = rowbase + w * 16 + lq * 4 + j;
      rnX[row] = 1.0f / fmaxf(sqrtf(ss[j]), 1e-12f);
    }
  }
}

// ---------------- kernel 8: GEMM with LDS-staged B via global_load_lds ----------------
// Packed sHatP ch-chunks (64KB) are contiguous in exactly consumption order ->
// global_load_lds with LINEAR dest (no swizzle needed); fragment reads are
// lane-linear ds_read_b128 (2 lanes/bank = free). 2-phase pipeline: STAGE(next)
// overlaps compute(cur), one barrier per ch. 8 waves x M=16 rows = 128 rows/block.
__global__ __launch_bounds__(512) void ace_kernel(const _Float16* __restrict__ xHat,
                                                  const _Float16* __restrict__ sHatP,
                                                  const float* __restrict__ rnX,
                                                  const int* __restrict__ labels,
                                                  float* __restrict__ outACE,
                                                  double* __restrict__ acc_loss) {
  __shared__ __align__(16) _Float16 Bsh[2][64 * 512];  // 2 x 64 KB
  __shared__ float part[32];
  const int tid = threadIdx.x;
  const int wid = tid >> 6, l = tid & 63, lr = l & 15, lq = l >> 4;
  const int rowbase = blockIdx.x * 128;
  const int wrow = rowbase + wid * 16;          // this wave's 16-row strip

  // A fragments (row wrow+lr, k = ks*32 + lq*8 .. +7)
  f16x8 a[8];
  {
    const _Float16* ap = xHat + (size_t)(wrow + lr) * D_ + lq * 8;
#pragma unroll
    for (int ks = 0; ks < 8; ++ks) a[ks] = *(const f16x8*)(ap + ks * 32);
  }

  int lab[4]; float rx[4], ssum[4], num[4];
#pragma unroll
  for (int j = 0; j < 4; ++j) {
    int row = wrow + lq * 4 + j;                // C-layout row for this lane
    lab[j] = labels[row];
    rx[j] = rnX[row];
    ssum[j] = 0.f; num[j] = 0.f;
  }

  // stage ch-chunk (64KB) into Bsh[buf]: 8 waves x 8 instrs x 1KB, linear
#define STAGE(bufi, chi) do {                                                        \
    const _Float16* _src = sHatP + (size_t)(chi) * 32768;                            \
    _Float16* _dst = &Bsh[bufi][0];                                                  \
    _Pragma("unroll")                                                                \
    for (int _s = 0; _s < 8; ++_s) {                                                 \
      const int _off = wid * 4096 + _s * 512;                                        \
      __builtin_amdgcn_global_load_lds(                                              \
          (const __attribute__((address_space(1))) unsigned int*)(_src + _off + l * 8), \
          (__attribute__((address_space(3))) unsigned int*)(_dst + _off), 16, 0, 0); \
    } } while (0)

  float* const outrow = outACE + (size_t)(wrow + lq * 4) * C_;

  STAGE(0, 0);
  __syncthreads();
  int buf = 0;
  for (int ch = 0; ch < 8; ++ch) {
    if (ch < 7) STAGE(buf ^ 1, ch + 1);
    const _Float16* bb = &Bsh[buf][(size_t)l * 8];
    f32x4 acc[8];
#pragma unroll
    for (int t = 0; t < 8; ++t) acc[t] = (f32x4){0.f, 0.f, 0.f, 0.f};
#pragma unroll
    for (int ks = 0; ks < 8; ++ks) {
#pragma unroll
      for (int t = 0; t < 8; ++t) {
        f16x8 bf = *(const f16x8*)(bb + (t * 8 + ks) * 512);
        acc[t] = __builtin_amdgcn_mfma_f32_16x16x32_f16(a[ks], bf, acc[t], 0, 0, 0);
      }
    }
#pragma unroll
    for (int t = 0; t < 8; ++t) {
      const int col = ch * 128 + t * 16 + lr;
      const bool valid = (col < C_);
#pragma unroll
      for (int j = 0; j < 4; ++j) {
        float v = acc[t][j] * rx[j];
        if (valid) outrow[(size_t)j * C_ + col] = v;
        ssum[j] += __expf(v - 1.0f);
        num[j] = (col == lab[j]) ? v : num[j];
      }
    }
    __syncthreads();   // drains this wave's stage loads (vmcnt) + syncs buffers
    buf ^= 1;
  }
#undef STAGE

#pragma unroll
  for (int d2 = 1; d2 < 16; d2 <<= 1) {
#pragma unroll
    for (int j = 0; j < 4; ++j) {
      ssum[j] += __shfl_xor(ssum[j], d2, 64);
      num[j]  += __shfl_xor(num[j], d2, 64);
    }
  }
  if (lr == 0 && lq == 0) {
    // lane 0 of each 16-lane group already holds the group's reduced value;
    // but reduction above only crossed lr (d2<16) -> values live per (lq) group.
  }
  if (lr == 0) {
    const float padcorr = 24.0f * __expf(-1.0f);
    float contrib = 0.f;
#pragma unroll
    for (int j = 0; j < 4; ++j)
      contrib += num[j] - (1.0f + __logf(ssum[j] - padcorr));
    part[wid * 4 + lq] = contrib;
  }
  __syncthreads();
  if (tid == 0) {
    float s = 0.f;
#pragma unroll
    for (int p2 = 0; p2 < 32; ++p2) s += part[p2];
    atomicAdd(acc_loss, (double)s);
  }
}

// ---------------- kernel 9: finalize loss ----------------
__global__ void fin_kernel(const double* a, float* out) {
  out[0] = (float)(-(*a) / (double)B_);
}

extern "C" void kernel_launch(void* const* d_in, const int* in_sizes, int n_in,
                              void* d_out, int out_size, void* d_ws, size_t ws_size,
                              hipStream_t stream) {
  const float* X      = (const float*)d_in[0];
  const int*   labels = (const int*)d_in[1];
  const float* S      = (const float*)d_in[2];
  const float* means  = (const float*)d_in[3];
  const float* bc     = (const float*)d_in[4];
  float* out = (float*)d_out;

  char* w = (char*)d_ws;
  double*    acc   = (double*)(w + 0);
  double*    C64   = (double*)(w + 256);          // 512 KB
  _Float16*  Wb    = (_Float16*)(w + 524544);     // 128 KB
  _Float16*  WbT   = (_Float16*)(w + 655616);     // 128 KB
  _Float16*  sHatP = (_Float16*)(w + 786688);     // 512 KB packed (1024 classes)
  float*     rnX   = (float*)(w + 1310976);       // 256 KB
  _Float16*  xHat  = (_Float16*)(w + 1573120);    // 32 MB
  float*     bcT   = (float*)(w + 1573120);       // aliases xHat (used before xform)

  transpose_kernel<<<64, 256, 0, stream>>>(bc, bcT, acc);
  cov_kernel<<<256, 256, 0, stream>>>(bc, bcT, C64);
  for (int p = 0; p < 4; ++p) {
    chol_panel<<<1, 256, 0, stream>>>(C64, p);
    int nt = 3 - p;
    if (nt > 0) chol_trail<<<nt * (nt + 1) / 2, 256, 0, stream>>>(C64, p);
  }
  inv_kernel<<<256, 256, 0, stream>>>(C64, Wb, WbT);
  sig_kernel<<<1024, 256, 0, stream>>>(S, WbT, sHatP);
  xform_kernel<<<1024, 256, 0, stream>>>(X, means, Wb, xHat, rnX);
  ace_kernel<<<512, 512, 0, stream>>>(xHat, sHatP, rnX, labels, out + 1, acc);
  fin_kernel<<<1, 1, 0, stream>>>(acc, out);
}

// Round 8
// 371.954 us; speedup vs baseline: 1.2575x; 1.0440x over previous
//
#include <hip/hip_runtime.h>
#include <hip/hip_bf16.h>
#include <math.h>

#define D_ 256
#define B_ 65536
#define C_ 1000

typedef _Float16 f16x8 __attribute__((ext_vector_type(8)));
typedef float f32x4 __attribute__((ext_vector_type(4)));

// ---------------- kernel 0: transpose bc (256x256 f32) + zero loss acc ----------------
__global__ void transpose_kernel(const float* __restrict__ in, float* __restrict__ out,
                                 double* __restrict__ acc) {
  __shared__ float t[32][33];
  if (blockIdx.x == 0 && threadIdx.x == 0) *acc = 0.0;
  const int bx = blockIdx.x & 7, by = blockIdx.x >> 3;
  const int lx = threadIdx.x & 31, ly = threadIdx.x >> 5;  // 32 x 8
#pragma unroll
  for (int s = 0; s < 4; ++s) {
    int r = by * 32 + ly + s * 8;
    t[ly + s * 8][lx] = in[r * 256 + bx * 32 + lx];
  }
  __syncthreads();
#pragma unroll
  for (int s = 0; s < 4; ++s) {
    int r = bx * 32 + ly + s * 8;
    out[r * 256 + by * 32 + lx] = t[lx][ly + s * 8];
  }
}

// ---------------- kernel 1: cov = bc @ bc^T in fp64 (coalesced via bcT) ----------------
__global__ void cov_kernel(const float* __restrict__ bc, const float* __restrict__ bcT,
                           double* __restrict__ C64) {
  const int i = blockIdx.x, j = threadIdx.x;
  __shared__ float ri[D_];
  ri[j] = bc[i * D_ + j];
  __syncthreads();
  double s = 0.0;
#pragma unroll 8
  for (int k = 0; k < D_; ++k) s += (double)ri[k] * (double)bcT[k * D_ + j];
  C64[i * D_ + j] = s;
}

// ---------------- kernel 2a: factor panel p (64 cols), rows in registers ----------------
__global__ __launch_bounds__(256, 1) void chol_panel(double* __restrict__ A, int p) {
  const int j0 = p * 64;
  const int r = threadIdx.x;
  __shared__ double rowv[64];
  __shared__ double dinv;
  double pr[64];
  const bool act = (r >= j0);
  if (act) {
#pragma unroll
    for (int k = 0; k < 64; ++k) pr[k] = A[(size_t)r * D_ + j0 + k];
  }
#pragma unroll
  for (int j = 0; j < 64; ++j) {
    const int col = j0 + j;
    if (r == col) { double d = sqrt(pr[j]); pr[j] = d; dinv = 1.0 / d; }
    __syncthreads();
    if (r > col) {
      double lr = pr[j] * dinv;
      pr[j] = lr;
      if (r < j0 + 64) rowv[r - j0] = lr;
    }
    __syncthreads();
    if (r > col) {
      const double lr = pr[j];
#pragma unroll
      for (int k = j + 1; k < 64; ++k) pr[k] -= lr * rowv[k];
    }
  }
  if (act) {
    const int kmax = (r - j0 < 63) ? (r - j0) : 63;
#pragma unroll
    for (int k = 0; k < 64; ++k)
      if (k <= kmax) A[(size_t)r * D_ + j0 + k] = pr[k];
  }
}

// ---------------- kernel 2b: trailing update for panel p, one block per 64x64 tile ----
__global__ __launch_bounds__(256) void chol_trail(double* __restrict__ A, int p) {
  const int j0 = p * 64;
  const int t0 = j0 + 64;
  int b = blockIdx.x, I = 0;
  while (b >= I + 1) { b -= I + 1; ++I; }   // lower tile pair (I,J), J<=I
  const int J = b;
  const int r0 = t0 + I * 64, c0 = t0 + J * 64;
  __shared__ double LR[64][67];
  __shared__ double LC[64][67];
  const int tid = threadIdx.x;
  for (int e = tid; e < 64 * 64; e += 256) {
    int rr = e >> 6, cc = e & 63;
    LR[rr][cc] = A[(size_t)(r0 + rr) * D_ + j0 + cc];
    LC[rr][cc] = A[(size_t)(c0 + rr) * D_ + j0 + cc];
  }
  __syncthreads();
  const int tx = tid & 15, ty = tid >> 4;
  double acc[4][4];
#pragma unroll
  for (int i = 0; i < 4; ++i)
#pragma unroll
    for (int j = 0; j < 4; ++j) acc[i][j] = 0.0;
#pragma unroll 4
  for (int k = 0; k < 64; ++k) {
    double a_[4], b_[4];
#pragma unroll
    for (int i = 0; i < 4; ++i) a_[i] = LR[ty + 16 * i][k];
#pragma unroll
    for (int j = 0; j < 4; ++j) b_[j] = LC[tx + 16 * j][k];
#pragma unroll
    for (int i = 0; i < 4; ++i)
#pragma unroll
      for (int j = 0; j < 4; ++j) acc[i][j] += a_[i] * b_[j];
  }
#pragma unroll
  for (int i = 0; i < 4; ++i) {
    const int grow = r0 + ty + 16 * i;
#pragma unroll
    for (int j = 0; j < 4; ++j) {
      const int gcol = c0 + tx + 16 * j;
      A[(size_t)grow * D_ + gcol] -= acc[i][j];
    }
  }
}

// ---------------- kernel 3: W = L^-1 column c + f16 emit (WbT row-major-T, WbP packed) -
__global__ __launch_bounds__(256) void inv_kernel(const double* __restrict__ L,
                                                  _Float16* __restrict__ WbP,
                                                  _Float16* __restrict__ WbT) {
  const int c = blockIdx.x;
  const int tid = threadIdx.x;
  __shared__ double w[D_];
  __shared__ double rdi[D_];
  __shared__ double rhs[32];
  __shared__ double Ldd[32][33];
  w[tid] = 0.0;
  rdi[tid] = 1.0 / L[(size_t)tid * D_ + tid];
  __syncthreads();
  const int q0 = c >> 5;
  for (int q = q0; q < 8; ++q) {
    const int i0 = q * 32;
    const int ii = tid >> 3, s = tid & 7;
    const int i = i0 + ii;
    double part = 0.0;
    for (int k = c + s; k < i0; k += 8) part += L[(size_t)i * D_ + k] * w[k];
    part += __shfl_xor(part, 1, 64);
    part += __shfl_xor(part, 2, 64);
    part += __shfl_xor(part, 4, 64);
    if (s == 0) rhs[ii] = ((i == c) ? 1.0 : 0.0) - part;
    for (int e = tid; e < 32 * 32; e += 256) {
      int rr = e >> 5, cc = e & 31;
      Ldd[rr][cc] = L[(size_t)(i0 + rr) * D_ + i0 + cc];
    }
    __syncthreads();
    if (tid < 32) {
      double x = rhs[tid];
      double v = 0.0;
      for (int j = 0; j < 32; ++j) {
        double xj = __shfl(x, j, 64);
        double wj = xj * rdi[i0 + j];
        if (tid == j) v = wj;
        if (tid > j) x -= Ldd[tid][j] * wj;
      }
      w[i0 + tid] = v;
    }
    __syncthreads();
  }
  _Float16 h = (_Float16)(float)w[tid];
  WbT[(size_t)c * D_ + tid] = h;   // WbT[k=c][i=tid], coalesced (sig uses this)
  // packed B layout: B-row n=tid (output col), k=c
  {
    const int g = tid >> 4, lrr = tid & 15;
    const int ks = c >> 5, lqq = (c >> 3) & 3, jj = c & 7;
    WbP[(size_t)(g * 8 + ks) * 512 + (size_t)(lqq * 16 + lrr) * 8 + jj] = h;
  }
}

// ---------------- kernel 5: signatures, normalized, packed MFMA-fragment layout -------
// sHatP: block (g,ks) of 512 elems at ((g*8+ks)*512); chunk l = 8 elems:
// col = g*16 + (l&15), k = ks*32 + (l>>4)*8 .. +7.
__global__ void sig_kernel(const float* __restrict__ S, const _Float16* __restrict__ WbT,
                           _Float16* __restrict__ sHatP) {
  int c = blockIdx.x, i = threadIdx.x;
  const int g = c >> 4, lr = c & 15;
  const int ks = i >> 5, lq = (i >> 3) & 3, jj = i & 7;
  const size_t off = (size_t)(g * 8 + ks) * 512 + (size_t)(lq * 16 + lr) * 8 + jj;
  if (c >= C_) { sHatP[off] = (_Float16)0.0f; return; }  // pad classes exactly 0
  __shared__ float srow[D_];
  __shared__ float wred[4];
  srow[i] = S[c * D_ + i];
  __syncthreads();
  float t = 0.f;
  for (int k = 0; k < D_; ++k) t += (float)WbT[k * D_ + i] * srow[k];
  float ss = t * t;
#pragma unroll
  for (int d = 1; d < 64; d <<= 1) ss += __shfl_xor(ss, d, 64);
  if ((i & 63) == 0) wred[i >> 6] = ss;
  __syncthreads();
  float tot = wred[0] + wred[1] + wred[2] + wred[3];
  float rn = 1.0f / fmaxf(sqrtf(tot), 1e-12f);
  sHatP[off] = (_Float16)(t * rn);
}

// ---------------- kernel 6: xHat_un = (X - m) @ W^T, ace-style (packed WbP, 1 barrier) -
// A fragments per-lane direct from X (f32 - mean -> f16, bitwise same as staged path).
// B staged ONCE via global_load_lds (128 KB linear), then barrier-free compute.
__global__ __launch_bounds__(512) void xform_kernel(const float* __restrict__ X,
                                                    const float* __restrict__ means,
                                                    const _Float16* __restrict__ WbP,
                                                    _Float16* __restrict__ xHat,
                                                    float* __restrict__ rnX) {
  __shared__ __align__(16) _Float16 Wsh[65536];  // 128 KB, both ch-chunks
  __shared__ float msh[D_];
  const int tid = threadIdx.x;
  const int wid = tid >> 6, l = tid & 63, lr = l & 15, lq = l >> 4;
  const int rowbase = blockIdx.x * 128;
  const int arow = rowbase + wid * 16 + lr;
  if (tid < 256) msh[tid] = means[tid];
#pragma unroll
  for (int s = 0; s < 16; ++s) {
    const int off = (wid * 16 + s) * 512;   // elements (1KB per instr per wave)
    __builtin_amdgcn_global_load_lds(
        (const __attribute__((address_space(1))) unsigned int*)(WbP + off + l * 8),
        (__attribute__((address_space(3))) unsigned int*)(&Wsh[off]), 16, 0, 0);
  }
  __syncthreads();

  f16x8 af[8];
#pragma unroll
  for (int ks = 0; ks < 8; ++ks) {
    const float* xp = X + (size_t)arow * D_ + lq * 8 + ks * 32;
    const float4 x0 = *(const float4*)(xp);
    const float4 x1 = *(const float4*)(xp + 4);
    const int mb = lq * 8 + ks * 32;
    af[ks][0] = (_Float16)(x0.x - msh[mb + 0]);
    af[ks][1] = (_Float16)(x0.y - msh[mb + 1]);
    af[ks][2] = (_Float16)(x0.z - msh[mb + 2]);
    af[ks][3] = (_Float16)(x0.w - msh[mb + 3]);
    af[ks][4] = (_Float16)(x1.x - msh[mb + 4]);
    af[ks][5] = (_Float16)(x1.y - msh[mb + 5]);
    af[ks][6] = (_Float16)(x1.z - msh[mb + 6]);
    af[ks][7] = (_Float16)(x1.w - msh[mb + 7]);
  }

  float ss[4] = {0.f, 0.f, 0.f, 0.f};
  const _Float16* bb = &Wsh[(size_t)l * 8];
  for (int ch = 0; ch < 2; ++ch) {
    f32x4 acc[8];
#pragma unroll
    for (int t = 0; t < 8; ++t) acc[t] = (f32x4){0.f, 0.f, 0.f, 0.f};
#pragma unroll
    for (int ks = 0; ks < 8; ++ks) {
#pragma unroll
      for (int t = 0; t < 8; ++t) {
        f16x8 bf = *(const f16x8*)(bb + (ch * 64 + t * 8 + ks) * 512);
        acc[t] = __builtin_amdgcn_mfma_f32_16x16x32_f16(af[ks], bf, acc[t], 0, 0, 0);
      }
    }
#pragma unroll
    for (int t = 0; t < 8; ++t) {
      const int col = ch * 128 + t * 16 + lr;
#pragma unroll
      for (int j = 0; j < 4; ++j) {
        const int row = rowbase + wid * 16 + lq * 4 + j;
        float v = acc[t][j];
        ss[j] += v * v;
        xHat[(size_t)row * D_ + col] = (_Float16)v;
      }
    }
  }
#pragma unroll
  for (int d = 1; d < 16; d <<= 1) {
#pragma unroll
    for (int j = 0; j < 4; ++j) ss[j] += __shfl_xor(ss[j], d, 64);
  }
  if (lr == 0) {
#pragma unroll
    for (int j = 0; j < 4; ++j) {
      const int row = rowbase + wid * 16 + lq * 4 + j;
      rnX[row] = 1.0f / fmaxf(sqrtf(ss[j]), 1e-12f);
    }
  }
}

// ---------------- kernel 8: GEMM, LDS B double-buffer, COUNTED vmcnt barriers (T4) ----
// Per ch: STAGE(next, 8 loads) -> compute -> 32 stores -> s_waitcnt vmcnt(32) +
// raw s_barrier. FIFO: at the wait, oldest ops are (<=32 prev stores, drained during
// compute) then the 8 stage loads -> loads guaranteed retired; THIS ch's stores fly
// across the barrier. ch 0..6 have exactly 32 unmasked stores (cols<1000). ch7: no stage.
__global__ __launch_bounds__(512) void ace_kernel(const _Float16* __restrict__ xHat,
                                                  const _Float16* __restrict__ sHatP,
                                                  const float* __restrict__ rnX,
                                                  const int* __restrict__ labels,
                                                  float* __restrict__ outACE,
                                                  double* __restrict__ acc_loss) {
  __shared__ __align__(16) _Float16 Bsh[2][64 * 512];  // 2 x 64 KB
  __shared__ float part[32];
  const int tid = threadIdx.x;
  const int wid = tid >> 6, l = tid & 63, lr = l & 15, lq = l >> 4;
  const int rowbase = blockIdx.x * 128;
  const int wrow = rowbase + wid * 16;          // this wave's 16-row strip

  f16x8 a[8];
  {
    const _Float16* ap = xHat + (size_t)(wrow + lr) * D_ + lq * 8;
#pragma unroll
    for (int ks = 0; ks < 8; ++ks) a[ks] = *(const f16x8*)(ap + ks * 32);
  }

  int lab[4]; float rx[4], ssum[4], num[4];
#pragma unroll
  for (int j = 0; j < 4; ++j) {
    int row = wrow + lq * 4 + j;                // C-layout row for this lane
    lab[j] = labels[row];
    rx[j] = rnX[row];
    ssum[j] = 0.f; num[j] = 0.f;
  }

#define STAGE(bufi, chi) do {                                                        \
    const _Float16* _src = sHatP + (size_t)(chi) * 32768;                            \
    _Float16* _dst = &Bsh[bufi][0];                                                  \
    _Pragma("unroll")                                                                \
    for (int _s = 0; _s < 8; ++_s) {                                                 \
      const int _off = wid * 4096 + _s * 512;                                        \
      __builtin_amdgcn_global_load_lds(                                              \
          (const __attribute__((address_space(1))) unsigned int*)(_src + _off + l * 8), \
          (__attribute__((address_space(3))) unsigned int*)(_dst + _off), 16, 0, 0); \
    } } while (0)

  float* const outrow = outACE + (size_t)(wrow + lq * 4) * C_;

  STAGE(0, 0);
  __syncthreads();                              // prologue: full drain once
  int buf = 0;
  for (int ch = 0; ch < 8; ++ch) {
    if (ch < 7) {
      STAGE(buf ^ 1, ch + 1);
      __builtin_amdgcn_sched_barrier(0);        // pin stage loads before compute/stores
    }
    const _Float16* bb = &Bsh[buf][(size_t)l * 8];
    f32x4 acc[8];
#pragma unroll
    for (int t = 0; t < 8; ++t) acc[t] = (f32x4){0.f, 0.f, 0.f, 0.f};
#pragma unroll
    for (int ks = 0; ks < 8; ++ks) {
#pragma unroll
      for (int t = 0; t < 8; ++t) {
        f16x8 bf = *(const f16x8*)(bb + (t * 8 + ks) * 512);
        acc[t] = __builtin_amdgcn_mfma_f32_16x16x32_f16(a[ks], bf, acc[t], 0, 0, 0);
      }
    }
#pragma unroll
    for (int t = 0; t < 8; ++t) {
      const int col = ch * 128 + t * 16 + lr;
      const bool valid = (col < C_);
#pragma unroll
      for (int j = 0; j < 4; ++j) {
        float v = acc[t][j] * rx[j];
        if (valid) outrow[(size_t)j * C_ + col] = v;
        ssum[j] += __expf(v - 1.0f);
        num[j] = (col == lab[j]) ? v : num[j];
      }
    }
    if (ch < 7) {
      __builtin_amdgcn_sched_barrier(0);
      asm volatile("s_waitcnt vmcnt(32)" ::: "memory");  // oldest 8 = stage loads done
      __builtin_amdgcn_s_barrier();
      __builtin_amdgcn_sched_barrier(0);
    }
    buf ^= 1;
  }
#undef STAGE

#pragma unroll
  for (int d2 = 1; d2 < 16; d2 <<= 1) {
#pragma unroll
    for (int j = 0; j < 4; ++j) {
      ssum[j] += __shfl_xor(ssum[j], d2, 64);
      num[j]  += __shfl_xor(num[j], d2, 64);
    }
  }
  if (lr == 0) {
    const float padcorr = 24.0f * __expf(-1.0f);
    float contrib = 0.f;
#pragma unroll
    for (int j = 0; j < 4; ++j)
      contrib += num[j] - (1.0f + __logf(ssum[j] - padcorr));
    part[wid * 4 + lq] = contrib;
  }
  __syncthreads();                              // final full drain + part[] visibility
  if (tid == 0) {
    float s = 0.f;
#pragma unroll
    for (int p2 = 0; p2 < 32; ++p2) s += part[p2];
    atomicAdd(acc_loss, (double)s);
  }
}

// ---------------- kernel 9: finalize loss ----------------
__global__ void fin_kernel(const double* a, float* out) {
  out[0] = (float)(-(*a) / (double)B_);
}

extern "C" void kernel_launch(void* const* d_in, const int* in_sizes, int n_in,
                              void* d_out, int out_size, void* d_ws, size_t ws_size,
                              hipStream_t stream) {
  const float* X      = (const float*)d_in[0];
  const int*   labels = (const int*)d_in[1];
  const float* S      = (const float*)d_in[2];
  const float* means  = (const float*)d_in[3];
  const float* bc     = (const float*)d_in[4];
  float* out = (float*)d_out;

  char* w = (char*)d_ws;
  double*    acc   = (double*)(w + 0);
  double*    C64   = (double*)(w + 256);          // 512 KB
  _Float16*  WbP   = (_Float16*)(w + 524544);     // 128 KB packed B (xform)
  _Float16*  WbT   = (_Float16*)(w + 655616);     // 128 KB (sig)
  _Float16*  sHatP = (_Float16*)(w + 786688);     // 512 KB packed (1024 classes)
  float*     rnX   = (float*)(w + 1310976);       // 256 KB
  _Float16*  xHat  = (_Float16*)(w + 1573120);    // 32 MB
  float*     bcT   = (float*)(w + 1573120);       // aliases xHat (used before xform)

  transpose_kernel<<<64, 256, 0, stream>>>(bc, bcT, acc);
  cov_kernel<<<256, 256, 0, stream>>>(bc, bcT, C64);
  for (int p = 0; p < 4; ++p) {
    chol_panel<<<1, 256, 0, stream>>>(C64, p);
    int nt = 3 - p;
    if (nt > 0) chol_trail<<<nt * (nt + 1) / 2, 256, 0, stream>>>(C64, p);
  }
  inv_kernel<<<256, 256, 0, stream>>>(C64, WbP, WbT);
  sig_kernel<<<1024, 256, 0, stream>>>(S, WbT, sHatP);
  xform_kernel<<<512, 512, 0, stream>>>(X, means, WbP, xHat, rnX);
  ace_kernel<<<512, 512, 0, stream>>>(xHat, sHatP, rnX, labels, out + 1, acc);
  fin_kernel<<<1, 1, 0, stream>>>(acc, out);
}

// Round 9
// 367.524 us; speedup vs baseline: 1.2726x; 1.0121x over previous
//
#include <hip/hip_runtime.h>
#include <hip/hip_bf16.h>
#include <math.h>

#define D_ 256
#define B_ 65536
#define C_ 1000

typedef _Float16 f16x8 __attribute__((ext_vector_type(8)));
typedef float f32x4 __attribute__((ext_vector_type(4)));

// ---------------- kernel 1: cov = bc @ bc^T in fp64, LDS-tiled (no transpose needed) --
__global__ __launch_bounds__(256) void cov_kernel(const float* __restrict__ bc,
                                                  double* __restrict__ C64,
                                                  double* __restrict__ acc) {
  __shared__ float Ash[32][260];
  __shared__ float Bsh2[32][260];
  const int b = blockIdx.x, bi = b >> 3, bj = b & 7;
  const int e = threadIdx.x;
  if (b == 0 && e == 0) *acc = 0.0;
#pragma unroll
  for (int s = 0; s < 32; ++s) {
    int lin = s * 256 + e;
    int rr = lin >> 8, cc = lin & 255;
    Ash[rr][cc] = bc[(bi * 32 + rr) * 256 + cc];
    Bsh2[rr][cc] = bc[(bj * 32 + rr) * 256 + cc];
  }
  __syncthreads();
  const int tx = e & 15, ty = e >> 4;
  double a00 = 0, a01 = 0, a10 = 0, a11 = 0;
#pragma unroll 8
  for (int k = 0; k < 256; ++k) {
    double ar0 = (double)Ash[ty][k], ar1 = (double)Ash[ty + 16][k];
    double br0 = (double)Bsh2[tx][k], br1 = (double)Bsh2[tx + 16][k];
    a00 += ar0 * br0; a01 += ar0 * br1;
    a10 += ar1 * br0; a11 += ar1 * br1;
  }
  const int r0 = bi * 32, c0 = bj * 32;
  C64[(size_t)(r0 + ty) * D_ + c0 + tx] = a00;
  C64[(size_t)(r0 + ty) * D_ + c0 + tx + 16] = a01;
  C64[(size_t)(r0 + ty + 16) * D_ + c0 + tx] = a10;
  C64[(size_t)(r0 + ty + 16) * D_ + c0 + tx + 16] = a11;
}

// ---------------- kernel 2a: factor panel p (64 cols) — 1 barrier/col, rsqrt-Newton ---
// raw[buf][k] holds the PRE-SCALE column-j value of panel row j0+k (written at the end
// of iteration j-1). Every lane redundantly computes rs = rsqrt(d2) (fp32 seed + 2
// fp64 Newton steps, rel err ~5e-11) -> no serial sqrt/div, no second barrier.
__global__ __launch_bounds__(256, 1) void chol_panel(double* __restrict__ A, int p) {
  const int j0 = p * 64;
  const int r = threadIdx.x;
  __shared__ double raw[2][64];
  double pr[64];
  const bool act = (r >= j0);
  const bool inpanel = act && (r < j0 + 64);
  if (act) {
#pragma unroll
    for (int k = 0; k < 64; ++k) pr[k] = A[(size_t)r * D_ + j0 + k];
  }
  if (inpanel) raw[0][r - j0] = pr[0];
  __syncthreads();
#pragma unroll
  for (int j = 0; j < 64; ++j) {
    const int col = j0 + j;
    const double d2 = raw[j & 1][j];
    double rs = (double)rsqrtf((float)d2);
    rs = rs * (1.5 - 0.5 * d2 * rs * rs);
    rs = rs * (1.5 - 0.5 * d2 * rs * rs);
    if (r >= col) {
      const double lr_ = pr[j] * rs;   // diag row: d2*rs = sqrt(d2)
      pr[j] = lr_;
#pragma unroll
      for (int k = j + 1; k < 64; ++k) pr[k] -= lr_ * (raw[j & 1][k] * rs);
    }
    if (j < 63) {
      if (r > col && r < j0 + 64) raw[(j + 1) & 1][r - j0] = pr[j + 1];
    }
    __syncthreads();
  }
  if (act) {
    const int kmax = (r - j0 < 63) ? (r - j0) : 63;
#pragma unroll
    for (int k = 0; k < 64; ++k)
      if (k <= kmax) A[(size_t)r * D_ + j0 + k] = pr[k];
  }
}

// ---------------- kernel 2b: trailing update for panel p, one block per 64x64 tile ----
__global__ __launch_bounds__(256) void chol_trail(double* __restrict__ A, int p) {
  const int j0 = p * 64;
  const int t0 = j0 + 64;
  int b = blockIdx.x, I = 0;
  while (b >= I + 1) { b -= I + 1; ++I; }   // lower tile pair (I,J), J<=I
  const int J = b;
  const int r0 = t0 + I * 64, c0 = t0 + J * 64;
  __shared__ double LR[64][67];
  __shared__ double LC[64][67];
  const int tid = threadIdx.x;
  for (int e = tid; e < 64 * 64; e += 256) {
    int rr = e >> 6, cc = e & 63;
    LR[rr][cc] = A[(size_t)(r0 + rr) * D_ + j0 + cc];
    LC[rr][cc] = A[(size_t)(c0 + rr) * D_ + j0 + cc];
  }
  __syncthreads();
  const int tx = tid & 15, ty = tid >> 4;
  double acc[4][4];
#pragma unroll
  for (int i = 0; i < 4; ++i)
#pragma unroll
    for (int j = 0; j < 4; ++j) acc[i][j] = 0.0;
#pragma unroll 4
  for (int k = 0; k < 64; ++k) {
    double a_[4], b_[4];
#pragma unroll
    for (int i = 0; i < 4; ++i) a_[i] = LR[ty + 16 * i][k];
#pragma unroll
    for (int j = 0; j < 4; ++j) b_[j] = LC[tx + 16 * j][k];
#pragma unroll
    for (int i = 0; i < 4; ++i)
#pragma unroll
      for (int j = 0; j < 4; ++j) acc[i][j] += a_[i] * b_[j];
  }
#pragma unroll
  for (int i = 0; i < 4; ++i) {
    const int grow = r0 + ty + 16 * i;
#pragma unroll
    for (int j = 0; j < 4; ++j) {
      const int gcol = c0 + tx + 16 * j;
      A[(size_t)grow * D_ + gcol] -= acc[i][j];
    }
  }
}

// ---------------- kernel 3: W = L^-1 column c + f16 emit (WbT row-major-T, WbP packed) -
__global__ __launch_bounds__(256) void inv_kernel(const double* __restrict__ L,
                                                  _Float16* __restrict__ WbP,
                                                  _Float16* __restrict__ WbT) {
  const int c = blockIdx.x;
  const int tid = threadIdx.x;
  __shared__ double w[D_];
  __shared__ double rdi[D_];
  __shared__ double rhs[32];
  __shared__ double Ldd[32][33];
  w[tid] = 0.0;
  rdi[tid] = 1.0 / L[(size_t)tid * D_ + tid];
  __syncthreads();
  const int q0 = c >> 5;
  for (int q = q0; q < 8; ++q) {
    const int i0 = q * 32;
    const int ii = tid >> 3, s = tid & 7;
    const int i = i0 + ii;
    double part = 0.0;
    for (int k = c + s; k < i0; k += 8) part += L[(size_t)i * D_ + k] * w[k];
    part += __shfl_xor(part, 1, 64);
    part += __shfl_xor(part, 2, 64);
    part += __shfl_xor(part, 4, 64);
    if (s == 0) rhs[ii] = ((i == c) ? 1.0 : 0.0) - part;
    for (int e = tid; e < 32 * 32; e += 256) {
      int rr = e >> 5, cc = e & 31;
      Ldd[rr][cc] = L[(size_t)(i0 + rr) * D_ + i0 + cc];
    }
    __syncthreads();
    if (tid < 32) {
      double x = rhs[tid];
      double v = 0.0;
      for (int j = 0; j < 32; ++j) {
        double xj = __shfl(x, j, 64);
        double wj = xj * rdi[i0 + j];
        if (tid == j) v = wj;
        if (tid > j) x -= Ldd[tid][j] * wj;
      }
      w[i0 + tid] = v;
    }
    __syncthreads();
  }
  _Float16 h = (_Float16)(float)w[tid];
  WbT[(size_t)c * D_ + tid] = h;   // WbT[k=c][i=tid], coalesced (sig uses this)
  {
    const int g = tid >> 4, lrr = tid & 15;
    const int ks = c >> 5, lqq = (c >> 3) & 3, jj = c & 7;
    WbP[(size_t)(g * 8 + ks) * 512 + (size_t)(lqq * 16 + lrr) * 8 + jj] = h;
  }
}

// ---------------- kernel 5: signatures, normalized, packed MFMA-fragment layout -------
__global__ void sig_kernel(const float* __restrict__ S, const _Float16* __restrict__ WbT,
                           _Float16* __restrict__ sHatP) {
  int c = blockIdx.x, i = threadIdx.x;
  const int g = c >> 4, lr = c & 15;
  const int ks = i >> 5, lq = (i >> 3) & 3, jj = i & 7;
  const size_t off = (size_t)(g * 8 + ks) * 512 + (size_t)(lq * 16 + lr) * 8 + jj;
  if (c >= C_) { sHatP[off] = (_Float16)0.0f; return; }  // pad classes exactly 0
  __shared__ float srow[D_];
  __shared__ float wred[4];
  srow[i] = S[c * D_ + i];
  __syncthreads();
  float t = 0.f;
  for (int k = 0; k < D_; ++k) t += (float)WbT[k * D_ + i] * srow[k];
  float ss = t * t;
#pragma unroll
  for (int d = 1; d < 64; d <<= 1) ss += __shfl_xor(ss, d, 64);
  if ((i & 63) == 0) wred[i >> 6] = ss;
  __syncthreads();
  float tot = wred[0] + wred[1] + wred[2] + wred[3];
  float rn = 1.0f / fmaxf(sqrtf(tot), 1e-12f);
  sHatP[off] = (_Float16)(t * rn);
}

// ---------------- kernel 6: xHat_un = (X - m) @ W^T, packed WbP, 1 barrier ------------
__global__ __launch_bounds__(512) void xform_kernel(const float* __restrict__ X,
                                                    const float* __restrict__ means,
                                                    const _Float16* __restrict__ WbP,
                                                    _Float16* __restrict__ xHat,
                                                    float* __restrict__ rnX) {
  __shared__ __align__(16) _Float16 Wsh[65536];  // 128 KB, both ch-chunks
  __shared__ float msh[D_];
  const int tid = threadIdx.x;
  const int wid = tid >> 6, l = tid & 63, lr = l & 15, lq = l >> 4;
  const int rowbase = blockIdx.x * 128;
  const int arow = rowbase + wid * 16 + lr;
  if (tid < 256) msh[tid] = means[tid];
#pragma unroll
  for (int s = 0; s < 16; ++s) {
    const int off = (wid * 16 + s) * 512;   // elements (1KB per instr per wave)
    __builtin_amdgcn_global_load_lds(
        (const __attribute__((address_space(1))) unsigned int*)(WbP + off + l * 8),
        (__attribute__((address_space(3))) unsigned int*)(&Wsh[off]), 16, 0, 0);
  }
  __syncthreads();

  f16x8 af[8];
#pragma unroll
  for (int ks = 0; ks < 8; ++ks) {
    const float* xp = X + (size_t)arow * D_ + lq * 8 + ks * 32;
    const float4 x0 = *(const float4*)(xp);
    const float4 x1 = *(const float4*)(xp + 4);
    const int mb = lq * 8 + ks * 32;
    af[ks][0] = (_Float16)(x0.x - msh[mb + 0]);
    af[ks][1] = (_Float16)(x0.y - msh[mb + 1]);
    af[ks][2] = (_Float16)(x0.z - msh[mb + 2]);
    af[ks][3] = (_Float16)(x0.w - msh[mb + 3]);
    af[ks][4] = (_Float16)(x1.x - msh[mb + 4]);
    af[ks][5] = (_Float16)(x1.y - msh[mb + 5]);
    af[ks][6] = (_Float16)(x1.z - msh[mb + 6]);
    af[ks][7] = (_Float16)(x1.w - msh[mb + 7]);
  }

  float ss[4] = {0.f, 0.f, 0.f, 0.f};
  const _Float16* bb = &Wsh[(size_t)l * 8];
  for (int ch = 0; ch < 2; ++ch) {
    f32x4 acc[8];
#pragma unroll
    for (int t = 0; t < 8; ++t) acc[t] = (f32x4){0.f, 0.f, 0.f, 0.f};
#pragma unroll
    for (int ks = 0; ks < 8; ++ks) {
#pragma unroll
      for (int t = 0; t < 8; ++t) {
        f16x8 bf = *(const f16x8*)(bb + (ch * 64 + t * 8 + ks) * 512);
        acc[t] = __builtin_amdgcn_mfma_f32_16x16x32_f16(af[ks], bf, acc[t], 0, 0, 0);
      }
    }
#pragma unroll
    for (int t = 0; t < 8; ++t) {
      const int col = ch * 128 + t * 16 + lr;
#pragma unroll
      for (int j = 0; j < 4; ++j) {
        const int row = rowbase + wid * 16 + lq * 4 + j;
        float v = acc[t][j];
        ss[j] += v * v;
        xHat[(size_t)row * D_ + col] = (_Float16)v;
      }
    }
  }
#pragma unroll
  for (int d = 1; d < 16; d <<= 1) {
#pragma unroll
    for (int j = 0; j < 4; ++j) ss[j] += __shfl_xor(ss[j], d, 64);
  }
  if (lr == 0) {
#pragma unroll
    for (int j = 0; j < 4; ++j) {
      const int row = rowbase + wid * 16 + lq * 4 + j;
      rnX[row] = 1.0f / fmaxf(sqrtf(ss[j]), 1e-12f);
    }
  }
}

// ---------------- kernel 8: GEMM, 1024 thr / 256 rows / grid 256 (1 block/CU, 1 pass) -
// LDS B double-buffer via global_load_lds; counted vmcnt barriers: per ch the queue is
// [4 stage loads][32 stores] -> s_waitcnt vmcnt(32) retires exactly the loads while
// stores fly across the raw s_barrier. 16 waves = 4/SIMD latency hiding.
__global__ __launch_bounds__(1024) void ace_kernel(const _Float16* __restrict__ xHat,
                                                   const _Float16* __restrict__ sHatP,
                                                   const float* __restrict__ rnX,
                                                   const int* __restrict__ labels,
                                                   float* __restrict__ outACE,
                                                   double* __restrict__ acc_loss) {
  __shared__ __align__(16) _Float16 Bsh[2][64 * 512];  // 2 x 64 KB
  __shared__ float part[64];
  const int tid = threadIdx.x;
  const int wid = tid >> 6, l = tid & 63, lr = l & 15, lq = l >> 4;
  const int rowbase = blockIdx.x * 256;
  const int wrow = rowbase + wid * 16;          // this wave's 16-row strip

  f16x8 a[8];
  {
    const _Float16* ap = xHat + (size_t)(wrow + lr) * D_ + lq * 8;
#pragma unroll
    for (int ks = 0; ks < 8; ++ks) a[ks] = *(const f16x8*)(ap + ks * 32);
  }

  int lab[4]; float rx[4], ssum[4], num[4];
#pragma unroll
  for (int j = 0; j < 4; ++j) {
    int row = wrow + lq * 4 + j;                // C-layout row for this lane
    lab[j] = labels[row];
    rx[j] = rnX[row];
    ssum[j] = 0.f; num[j] = 0.f;
  }

  // stage ch-chunk (64KB): 16 waves x 4 instrs x 1KB, linear
#define STAGE(bufi, chi) do {                                                        \
    const _Float16* _src = sHatP + (size_t)(chi) * 32768;                            \
    _Float16* _dst = &Bsh[bufi][0];                                                  \
    _Pragma("unroll")                                                                \
    for (int _s = 0; _s < 4; ++_s) {                                                 \
      const int _off = wid * 2048 + _s * 512;                                        \
      __builtin_amdgcn_global_load_lds(                                              \
          (const __attribute__((address_space(1))) unsigned int*)(_src + _off + l * 8), \
          (__attribute__((address_space(3))) unsigned int*)(_dst + _off), 16, 0, 0); \
    } } while (0)

  float* const outrow = outACE + (size_t)(wrow + lq * 4) * C_;

  STAGE(0, 0);
  __syncthreads();                              // prologue: full drain once
  int buf = 0;
  for (int ch = 0; ch < 8; ++ch) {
    if (ch < 7) {
      STAGE(buf ^ 1, ch + 1);
      __builtin_amdgcn_sched_barrier(0);        // pin stage loads before compute/stores
    }
    const _Float16* bb = &Bsh[buf][(size_t)l * 8];
    f32x4 acc[8];
#pragma unroll
    for (int t = 0; t < 8; ++t) acc[t] = (f32x4){0.f, 0.f, 0.f, 0.f};
#pragma unroll
    for (int ks = 0; ks < 8; ++ks) {
#pragma unroll
      for (int t = 0; t < 8; ++t) {
        f16x8 bf = *(const f16x8*)(bb + (t * 8 + ks) * 512);
        acc[t] = __builtin_amdgcn_mfma_f32_16x16x32_f16(a[ks], bf, acc[t], 0, 0, 0);
      }
    }
#pragma unroll
    for (int t = 0; t < 8; ++t) {
      const int col = ch * 128 + t * 16 + lr;
      const bool valid = (col < C_);
#pragma unroll
      for (int j = 0; j < 4; ++j) {
        float v = acc[t][j] * rx[j];
        if (valid) outrow[(size_t)j * C_ + col] = v;
        ssum[j] += __expf(v - 1.0f);
        num[j] = (col == lab[j]) ? v : num[j];
      }
    }
    if (ch < 7) {
      __builtin_amdgcn_sched_barrier(0);
      asm volatile("s_waitcnt vmcnt(32)" ::: "memory");  // retires the 4 stage loads
      __builtin_amdgcn_s_barrier();
      __builtin_amdgcn_sched_barrier(0);
    }
    buf ^= 1;
  }
#undef STAGE

#pragma unroll
  for (int d2 = 1; d2 < 16; d2 <<= 1) {
#pragma unroll
    for (int j = 0; j < 4; ++j) {
      ssum[j] += __shfl_xor(ssum[j], d2, 64);
      num[j]  += __shfl_xor(num[j], d2, 64);
    }
  }
  if (lr == 0) {
    const float padcorr = 24.0f * __expf(-1.0f);
    float contrib = 0.f;
#pragma unroll
    for (int j = 0; j < 4; ++j)
      contrib += num[j] - (1.0f + __logf(ssum[j] - padcorr));
    part[wid * 4 + lq] = contrib;
  }
  __syncthreads();                              // final full drain + part[] visibility
  if (tid == 0) {
    float s = 0.f;
#pragma unroll
    for (int p2 = 0; p2 < 64; ++p2) s += part[p2];
    atomicAdd(acc_loss, (double)s);
  }
}

// ---------------- kernel 9: finalize loss ----------------
__global__ void fin_kernel(const double* a, float* out) {
  out[0] = (float)(-(*a) / (double)B_);
}

extern "C" void kernel_launch(void* const* d_in, const int* in_sizes, int n_in,
                              void* d_out, int out_size, void* d_ws, size_t ws_size,
                              hipStream_t stream) {
  const float* X      = (const float*)d_in[0];
  const int*   labels = (const int*)d_in[1];
  const float* S      = (const float*)d_in[2];
  const float* means  = (const float*)d_in[3];
  const float* bc     = (const float*)d_in[4];
  float* out = (float*)d_out;

  char* w = (char*)d_ws;
  double*    acc   = (double*)(w + 0);
  double*    C64   = (double*)(w + 256);          // 512 KB
  _Float16*  WbP   = (_Float16*)(w + 524544);     // 128 KB packed B (xform)
  _Float16*  WbT   = (_Float16*)(w + 655616);     // 128 KB (sig)
  _Float16*  sHatP = (_Float16*)(w + 786688);     // 512 KB packed (1024 classes)
  float*     rnX   = (float*)(w + 1310976);       // 256 KB
  _Float16*  xHat  = (_Float16*)(w + 1573120);    // 32 MB

  cov_kernel<<<64, 256, 0, stream>>>(bc, C64, acc);
  for (int p = 0; p < 4; ++p) {
    chol_panel<<<1, 256, 0, stream>>>(C64, p);
    int nt = 3 - p;
    if (nt > 0) chol_trail<<<nt * (nt + 1) / 2, 256, 0, stream>>>(C64, p);
  }
  inv_kernel<<<256, 256, 0, stream>>>(C64, WbP, WbT);
  sig_kernel<<<1024, 256, 0, stream>>>(S, WbT, sHatP);
  xform_kernel<<<512, 512, 0, stream>>>(X, means, WbP, xHat, rnX);
  ace_kernel<<<256, 1024, 0, stream>>>(xHat, sHatP, rnX, labels, out + 1, acc);
  fin_kernel<<<1, 1, 0, stream>>>(acc, out);
}

// Round 10
// 358.490 us; speedup vs baseline: 1.3047x; 1.0252x over previous
//
#include <hip/hip_runtime.h>
#include <hip/hip_bf16.h>
#include <math.h>

#define D_ 256
#define B_ 65536
#define C_ 1000

typedef _Float16 f16x8 __attribute__((ext_vector_type(8)));
typedef float f32x4 __attribute__((ext_vector_type(4)));

// ---------------- kernel 1: cov = bc @ bc^T in fp64, LDS-tiled; zeroes acc+counter ----
__global__ __launch_bounds__(256) void cov_kernel(const float* __restrict__ bc,
                                                  double* __restrict__ C64,
                                                  double* __restrict__ acc,
                                                  unsigned int* __restrict__ counter) {
  __shared__ float Ash[32][260];
  __shared__ float Bsh2[32][260];
  const int b = blockIdx.x, bi = b >> 3, bj = b & 7;
  const int e = threadIdx.x;
  if (b == 0 && e == 0) { *acc = 0.0; *counter = 0u; }
#pragma unroll
  for (int s = 0; s < 32; ++s) {
    int lin = s * 256 + e;
    int rr = lin >> 8, cc = lin & 255;
    Ash[rr][cc] = bc[(bi * 32 + rr) * 256 + cc];
    Bsh2[rr][cc] = bc[(bj * 32 + rr) * 256 + cc];
  }
  __syncthreads();
  const int tx = e & 15, ty = e >> 4;
  double a00 = 0, a01 = 0, a10 = 0, a11 = 0;
#pragma unroll 8
  for (int k = 0; k < 256; ++k) {
    double ar0 = (double)Ash[ty][k], ar1 = (double)Ash[ty + 16][k];
    double br0 = (double)Bsh2[tx][k], br1 = (double)Bsh2[tx + 16][k];
    a00 += ar0 * br0; a01 += ar0 * br1;
    a10 += ar1 * br0; a11 += ar1 * br1;
  }
  const int r0 = bi * 32, c0 = bj * 32;
  C64[(size_t)(r0 + ty) * D_ + c0 + tx] = a00;
  C64[(size_t)(r0 + ty) * D_ + c0 + tx + 16] = a01;
  C64[(size_t)(r0 + ty + 16) * D_ + c0 + tx] = a10;
  C64[(size_t)(r0 + ty + 16) * D_ + c0 + tx + 16] = a11;
}

// ---------------- kernel 2a: factor panel p (64 cols) — 1 barrier/col, rsqrt-Newton ---
__global__ __launch_bounds__(256, 1) void chol_panel(double* __restrict__ A, int p) {
  const int j0 = p * 64;
  const int r = threadIdx.x;
  __shared__ double raw[2][64];
  double pr[64];
  const bool act = (r >= j0);
  const bool inpanel = act && (r < j0 + 64);
  if (act) {
#pragma unroll
    for (int k = 0; k < 64; ++k) pr[k] = A[(size_t)r * D_ + j0 + k];
  }
  if (inpanel) raw[0][r - j0] = pr[0];
  __syncthreads();
#pragma unroll
  for (int j = 0; j < 64; ++j) {
    const int col = j0 + j;
    const double d2 = raw[j & 1][j];
    double rs = (double)rsqrtf((float)d2);
    rs = rs * (1.5 - 0.5 * d2 * rs * rs);
    rs = rs * (1.5 - 0.5 * d2 * rs * rs);
    if (r >= col) {
      const double lr_ = pr[j] * rs;   // diag row: d2*rs = sqrt(d2)
      pr[j] = lr_;
#pragma unroll
      for (int k = j + 1; k < 64; ++k) pr[k] -= lr_ * (raw[j & 1][k] * rs);
    }
    if (j < 63) {
      if (r > col && r < j0 + 64) raw[(j + 1) & 1][r - j0] = pr[j + 1];
    }
    __syncthreads();
  }
  if (act) {
    const int kmax = (r - j0 < 63) ? (r - j0) : 63;
#pragma unroll
    for (int k = 0; k < 64; ++k)
      if (k <= kmax) A[(size_t)r * D_ + j0 + k] = pr[k];
  }
}

// ---------------- kernel 2b: trailing update for panel p, one block per 64x64 tile ----
__global__ __launch_bounds__(256) void chol_trail(double* __restrict__ A, int p) {
  const int j0 = p * 64;
  const int t0 = j0 + 64;
  int b = blockIdx.x, I = 0;
  while (b >= I + 1) { b -= I + 1; ++I; }   // lower tile pair (I,J), J<=I
  const int J = b;
  const int r0 = t0 + I * 64, c0 = t0 + J * 64;
  __shared__ double LR[64][67];
  __shared__ double LC[64][67];
  const int tid = threadIdx.x;
  for (int e = tid; e < 64 * 64; e += 256) {
    int rr = e >> 6, cc = e & 63;
    LR[rr][cc] = A[(size_t)(r0 + rr) * D_ + j0 + cc];
    LC[rr][cc] = A[(size_t)(c0 + rr) * D_ + j0 + cc];
  }
  __syncthreads();
  const int tx = tid & 15, ty = tid >> 4;
  double acc[4][4];
#pragma unroll
  for (int i = 0; i < 4; ++i)
#pragma unroll
    for (int j = 0; j < 4; ++j) acc[i][j] = 0.0;
#pragma unroll 4
  for (int k = 0; k < 64; ++k) {
    double a_[4], b_[4];
#pragma unroll
    for (int i = 0; i < 4; ++i) a_[i] = LR[ty + 16 * i][k];
#pragma unroll
    for (int j = 0; j < 4; ++j) b_[j] = LC[tx + 16 * j][k];
#pragma unroll
    for (int i = 0; i < 4; ++i)
#pragma unroll
      for (int j = 0; j < 4; ++j) acc[i][j] += a_[i] * b_[j];
  }
#pragma unroll
  for (int i = 0; i < 4; ++i) {
    const int grow = r0 + ty + 16 * i;
#pragma unroll
    for (int j = 0; j < 4; ++j) {
      const int gcol = c0 + tx + 16 * j;
      A[(size_t)grow * D_ + gcol] -= acc[i][j];
    }
  }
}

// ---------------- kernel 3: W = L^-1 column c + f16 emit (WbT row-major-T, WbP packed) -
__global__ __launch_bounds__(256) void inv_kernel(const double* __restrict__ L,
                                                  _Float16* __restrict__ WbP,
                                                  _Float16* __restrict__ WbT) {
  const int c = blockIdx.x;
  const int tid = threadIdx.x;
  __shared__ double w[D_];
  __shared__ double rdi[D_];
  __shared__ double rhs[32];
  __shared__ double Ldd[32][33];
  w[tid] = 0.0;
  rdi[tid] = 1.0 / L[(size_t)tid * D_ + tid];
  __syncthreads();
  const int q0 = c >> 5;
  for (int q = q0; q < 8; ++q) {
    const int i0 = q * 32;
    const int ii = tid >> 3, s = tid & 7;
    const int i = i0 + ii;
    double part = 0.0;
    for (int k = c + s; k < i0; k += 8) part += L[(size_t)i * D_ + k] * w[k];
    part += __shfl_xor(part, 1, 64);
    part += __shfl_xor(part, 2, 64);
    part += __shfl_xor(part, 4, 64);
    if (s == 0) rhs[ii] = ((i == c) ? 1.0 : 0.0) - part;
    for (int e = tid; e < 32 * 32; e += 256) {
      int rr = e >> 5, cc = e & 31;
      Ldd[rr][cc] = L[(size_t)(i0 + rr) * D_ + i0 + cc];
    }
    __syncthreads();
    if (tid < 32) {
      double x = rhs[tid];
      double v = 0.0;
      for (int j = 0; j < 32; ++j) {
        double xj = __shfl(x, j, 64);
        double wj = xj * rdi[i0 + j];
        if (tid == j) v = wj;
        if (tid > j) x -= Ldd[tid][j] * wj;
      }
      w[i0 + tid] = v;
    }
    __syncthreads();
  }
  _Float16 h = (_Float16)(float)w[tid];
  WbT[(size_t)c * D_ + tid] = h;   // WbT[k=c][i=tid], coalesced (sig uses this)
  {
    const int g = tid >> 4, lrr = tid & 15;
    const int ks = c >> 5, lqq = (c >> 3) & 3, jj = c & 7;
    WbP[(size_t)(g * 8 + ks) * 512 + (size_t)(lqq * 16 + lrr) * 8 + jj] = h;
  }
}

// ---------------- kernel 5: signatures, normalized, packed MFMA-fragment layout -------
__global__ void sig_kernel(const float* __restrict__ S, const _Float16* __restrict__ WbT,
                           _Float16* __restrict__ sHatP) {
  int c = blockIdx.x, i = threadIdx.x;
  const int g = c >> 4, lr = c & 15;
  const int ks = i >> 5, lq = (i >> 3) & 3, jj = i & 7;
  const size_t off = (size_t)(g * 8 + ks) * 512 + (size_t)(lq * 16 + lr) * 8 + jj;
  if (c >= C_) { sHatP[off] = (_Float16)0.0f; return; }  // pad classes exactly 0
  __shared__ float srow[D_];
  __shared__ float wred[4];
  srow[i] = S[c * D_ + i];
  __syncthreads();
  float t = 0.f;
  for (int k = 0; k < D_; ++k) t += (float)WbT[k * D_ + i] * srow[k];
  float ss = t * t;
#pragma unroll
  for (int d = 1; d < 64; d <<= 1) ss += __shfl_xor(ss, d, 64);
  if ((i & 63) == 0) wred[i >> 6] = ss;
  __syncthreads();
  float tot = wred[0] + wred[1] + wred[2] + wred[3];
  float rn = 1.0f / fmaxf(sqrtf(tot), 1e-12f);
  sHatP[off] = (_Float16)(t * rn);
}

// ---------------- kernel 8: FUSED whiten + GEMM + logsumexp + finalize ----------------
// Per block (256 rows, 16 waves): stage WbP (128KB LDS) -> whiten rows via MFMA from X
// (bitwise same as old xform) -> round-trip whitened strip through swizzled LDS (no
// xHat in HBM) -> reuse LDS for sHatP double-buffer -> R9 counted-vmcnt main loop ->
// loss reduce; LAST block (completion counter) writes out[0]. No xform/fin kernels.
__global__ __launch_bounds__(1024) void ace_kernel(const float* __restrict__ X,
                                                   const float* __restrict__ means,
                                                   const _Float16* __restrict__ WbP,
                                                   const _Float16* __restrict__ sHatP,
                                                   const int* __restrict__ labels,
                                                   float* __restrict__ out,
                                                   double* __restrict__ acc_loss,
                                                   unsigned int* __restrict__ counter) {
  __shared__ __align__(16) char ldsraw[131072];  // phase1: Wsh | phase2: xs | phase3: Bsh[2]
  __shared__ float msh[D_];
  __shared__ float part[64];
  _Float16* const Wsh = (_Float16*)ldsraw;
  char* const xsC = ldsraw;
  _Float16* const Bsh = (_Float16*)ldsraw;       // [2][32768]
  float* const outACE = out + 1;

  const int tid = threadIdx.x;
  const int wid = tid >> 6, l = tid & 63, lr = l & 15, lq = l >> 4;
  const int rowbase = blockIdx.x * 256;
  const int wrow = rowbase + wid * 16;           // this wave's 16-row strip
  const int arow = wrow + lr;                    // A-operand row (global)

  // ---- phase 1: stage WbP (128 KB) ----
  if (tid < 256) msh[tid] = means[tid];
#pragma unroll
  for (int s = 0; s < 8; ++s) {
    const int off = (wid * 8 + s) * 512;
    __builtin_amdgcn_global_load_lds(
        (const __attribute__((address_space(1))) unsigned int*)(WbP + off + l * 8),
        (__attribute__((address_space(3))) unsigned int*)(Wsh + off), 16, 0, 0);
  }
  __syncthreads();

  // ---- phase 2: whiten (X - m) @ W^T for this wave's 16 rows ----
  f16x8 af[8];
#pragma unroll
  for (int ks = 0; ks < 8; ++ks) {
    const float* xp = X + (size_t)arow * D_ + lq * 8 + ks * 32;
    const float4 x0 = *(const float4*)(xp);
    const float4 x1 = *(const float4*)(xp + 4);
    const int mb = lq * 8 + ks * 32;
    af[ks][0] = (_Float16)(x0.x - msh[mb + 0]);
    af[ks][1] = (_Float16)(x0.y - msh[mb + 1]);
    af[ks][2] = (_Float16)(x0.z - msh[mb + 2]);
    af[ks][3] = (_Float16)(x0.w - msh[mb + 3]);
    af[ks][4] = (_Float16)(x1.x - msh[mb + 4]);
    af[ks][5] = (_Float16)(x1.y - msh[mb + 5]);
    af[ks][6] = (_Float16)(x1.z - msh[mb + 6]);
    af[ks][7] = (_Float16)(x1.w - msh[mb + 7]);
  }
  f32x4 wacc[16];
#pragma unroll
  for (int u = 0; u < 16; ++u) wacc[u] = (f32x4){0.f, 0.f, 0.f, 0.f};
  {
    const _Float16* wb = Wsh + (size_t)l * 8;
#pragma unroll
    for (int ks = 0; ks < 8; ++ks) {
#pragma unroll
      for (int u = 0; u < 16; ++u) {
        f16x8 bf = *(const f16x8*)(wb + (u * 8 + ks) * 512);
        wacc[u] = __builtin_amdgcn_mfma_f32_16x16x32_f16(af[ks], bf, wacc[u], 0, 0, 0);
      }
    }
  }
  // row norms (C-layout rows) -> rx in registers
  float ss[4] = {0.f, 0.f, 0.f, 0.f};
#pragma unroll
  for (int u = 0; u < 16; ++u)
#pragma unroll
    for (int j = 0; j < 4; ++j) ss[j] += wacc[u][j] * wacc[u][j];
#pragma unroll
  for (int d = 1; d < 16; d <<= 1) {
#pragma unroll
    for (int j = 0; j < 4; ++j) ss[j] += __shfl_xor(ss[j], d, 64);
  }
  float rx[4];
#pragma unroll
  for (int j = 0; j < 4; ++j) rx[j] = 1.0f / fmaxf(sqrtf(ss[j]), 1e-12f);

  __syncthreads();   // all waves done reading Wsh

  // ---- write whitened strip to LDS (swizzled), re-read as A-fragments ----
#pragma unroll
  for (int u = 0; u < 16; ++u) {
#pragma unroll
    for (int j = 0; j < 4; ++j) {
      const int rowl = wid * 16 + lq * 4 + j;
      const int byte = (rowl * 512 + (u * 16 + lr) * 2) ^ ((rowl & 7) << 4);
      *(_Float16*)(xsC + byte) = (_Float16)wacc[u][j];
    }
  }
  __syncthreads();   // writes visible
  f16x8 a[8];
  {
    const int rowA = wid * 16 + lr;
#pragma unroll
    for (int ks = 0; ks < 8; ++ks) {
      const int byte = (rowA * 512 + ks * 64 + lq * 16) ^ ((rowA & 7) << 4);
      a[ks] = *(const f16x8*)(xsC + byte);
    }
  }
  __syncthreads();   // all A-frag reads done before Bsh staging overwrites

  // ---- phase 3: main GEMM over classes, LDS B double-buffer, counted vmcnt ----
  int lab[4]; float ssum[4], num[4];
#pragma unroll
  for (int j = 0; j < 4; ++j) {
    lab[j] = labels[wrow + lq * 4 + j];
    ssum[j] = 0.f; num[j] = 0.f;
  }

#define STAGE(bufi, chi) do {                                                        \
    const _Float16* _src = sHatP + (size_t)(chi) * 32768;                            \
    _Float16* _dst = Bsh + (size_t)(bufi) * 32768;                                   \
    _Pragma("unroll")                                                                \
    for (int _s = 0; _s < 4; ++_s) {                                                 \
      const int _off = wid * 2048 + _s * 512;                                        \
      __builtin_amdgcn_global_load_lds(                                              \
          (const __attribute__((address_space(1))) unsigned int*)(_src + _off + l * 8), \
          (__attribute__((address_space(3))) unsigned int*)(_dst + _off), 16, 0, 0); \
    } } while (0)

  float* const outrow = outACE + (size_t)(wrow + lq * 4) * C_;

  STAGE(0, 0);
  __syncthreads();                              // prologue: full drain once
  int buf = 0;
  for (int ch = 0; ch < 8; ++ch) {
    if (ch < 7) {
      STAGE(buf ^ 1, ch + 1);
      __builtin_amdgcn_sched_barrier(0);        // pin stage loads before compute/stores
    }
    const _Float16* bb = Bsh + (size_t)buf * 32768 + (size_t)l * 8;
    f32x4 acc[8];
#pragma unroll
    for (int t = 0; t < 8; ++t) acc[t] = (f32x4){0.f, 0.f, 0.f, 0.f};
#pragma unroll
    for (int ks = 0; ks < 8; ++ks) {
#pragma unroll
      for (int t = 0; t < 8; ++t) {
        f16x8 bf = *(const f16x8*)(bb + (t * 8 + ks) * 512);
        acc[t] = __builtin_amdgcn_mfma_f32_16x16x32_f16(a[ks], bf, acc[t], 0, 0, 0);
      }
    }
#pragma unroll
    for (int t = 0; t < 8; ++t) {
      const int col = ch * 128 + t * 16 + lr;
      const bool valid = (col < C_);
#pragma unroll
      for (int j = 0; j < 4; ++j) {
        float v = acc[t][j] * rx[j];
        if (valid) outrow[(size_t)j * C_ + col] = v;
        ssum[j] += __expf(v - 1.0f);
        num[j] = (col == lab[j]) ? v : num[j];
      }
    }
    if (ch < 7) {
      __builtin_amdgcn_sched_barrier(0);
      asm volatile("s_waitcnt vmcnt(32)" ::: "memory");  // retires the 4 stage loads
      __builtin_amdgcn_s_barrier();
      __builtin_amdgcn_sched_barrier(0);
    }
    buf ^= 1;
  }
#undef STAGE

#pragma unroll
  for (int d2 = 1; d2 < 16; d2 <<= 1) {
#pragma unroll
    for (int j = 0; j < 4; ++j) {
      ssum[j] += __shfl_xor(ssum[j], d2, 64);
      num[j]  += __shfl_xor(num[j], d2, 64);
    }
  }
  if (lr == 0) {
    const float padcorr = 24.0f * __expf(-1.0f);
    float contrib = 0.f;
#pragma unroll
    for (int j = 0; j < 4; ++j)
      contrib += num[j] - (1.0f + __logf(ssum[j] - padcorr));
    part[wid * 4 + lq] = contrib;
  }
  __syncthreads();
  if (tid == 0) {
    float s = 0.f;
#pragma unroll
    for (int p2 = 0; p2 < 64; ++p2) s += part[p2];
    atomicAdd(acc_loss, (double)s);
    __threadfence();
    unsigned int old = atomicAdd(counter, 1u);
    if (old == (unsigned int)(gridDim.x - 1)) {
      __threadfence();
      double tot = atomicAdd(acc_loss, 0.0);    // coherent read of final sum
      out[0] = (float)(-tot / (double)B_);
    }
  }
}

extern "C" void kernel_launch(void* const* d_in, const int* in_sizes, int n_in,
                              void* d_out, int out_size, void* d_ws, size_t ws_size,
                              hipStream_t stream) {
  const float* X      = (const float*)d_in[0];
  const int*   labels = (const int*)d_in[1];
  const float* S      = (const float*)d_in[2];
  const float* means  = (const float*)d_in[3];
  const float* bc     = (const float*)d_in[4];
  float* out = (float*)d_out;

  char* w = (char*)d_ws;
  double*       acc   = (double*)(w + 0);
  unsigned int* cnt   = (unsigned int*)(w + 128);
  double*       C64   = (double*)(w + 256);       // 512 KB
  _Float16*     WbP   = (_Float16*)(w + 524544);  // 128 KB packed B (whiten)
  _Float16*     WbT   = (_Float16*)(w + 655616);  // 128 KB (sig)
  _Float16*     sHatP = (_Float16*)(w + 786688);  // 512 KB packed (1024 classes)

  cov_kernel<<<64, 256, 0, stream>>>(bc, C64, acc, cnt);
  for (int p = 0; p < 4; ++p) {
    chol_panel<<<1, 256, 0, stream>>>(C64, p);
    int nt = 3 - p;
    if (nt > 0) chol_trail<<<nt * (nt + 1) / 2, 256, 0, stream>>>(C64, p);
  }
  inv_kernel<<<256, 256, 0, stream>>>(C64, WbP, WbT);
  sig_kernel<<<1024, 256, 0, stream>>>(S, WbT, sHatP);
  ace_kernel<<<256, 1024, 0, stream>>>(X, means, WbP, sHatP, labels, out, acc, cnt);
}